// Round 1
// baseline (3006.013 us; speedup 1.0000x reference)
//
#include <hip/hip_runtime.h>
#include <cstdio>
#include <cmath>

#define NUM_WORDS 2048
#define NUM_CAND 8192
#define HIDDEN 768
#define FEAT 20
#define FFNN_DIM 1000
#define SPAN_DIM 2324
#define TOP_NUM 819
#define MSW 30

// d_out layout (floats): [scores 8192][top_idx 819][top_starts 819][top_ends 819]
//                        [top_span_emb 819*2324][top_scores 819]
#define OUT_TOPIDX   (NUM_CAND)
#define OUT_TSTART   (NUM_CAND + TOP_NUM)
#define OUT_TEND     (NUM_CAND + 2*TOP_NUM)
#define OUT_TEMB     (NUM_CAND + 3*TOP_NUM)
#define OUT_TSCORE   (NUM_CAND + 3*TOP_NUM + TOP_NUM*SPAN_DIM)

// ---------------- head scores: doc @ head_w + head_b  -> [2048] ----------------
__global__ void head_kernel(const float* __restrict__ doc, const float* __restrict__ hw,
                            const float* __restrict__ hb, float* __restrict__ out) {
    int wave = threadIdx.x >> 6, lane = threadIdx.x & 63;
    int row = blockIdx.x * 4 + wave;
    if (row >= NUM_WORDS) return;
    float acc = 0.f;
    for (int h = lane; h < HIDDEN; h += 64) acc += doc[row * HIDDEN + h] * hw[h];
    for (int off = 32; off > 0; off >>= 1) acc += __shfl_down(acc, off);
    if (lane == 0) out[row] = acc + hb[0];
}

// ---------------- width prior ffnn: [30,20] -> [30] ----------------
__global__ void width_kernel(const float* __restrict__ x, const float* __restrict__ w1,
                             const float* __restrict__ b1, const float* __restrict__ w2,
                             const float* __restrict__ b2, const float* __restrict__ w3,
                             const float* __restrict__ b3, float* __restrict__ out) {
    __shared__ float xs[FEAT];
    __shared__ float h1s[FFNN_DIM];
    __shared__ float red[256];
    int r = blockIdx.x, t = threadIdx.x;
    if (t < FEAT) xs[t] = x[r * FEAT + t];
    __syncthreads();
    for (int j = t; j < FFNN_DIM; j += 256) {
        float acc = b1[j];
        for (int k = 0; k < FEAT; ++k) acc += xs[k] * w1[k * FFNN_DIM + j];
        h1s[j] = fmaxf(acc, 0.f);
    }
    __syncthreads();
    float partial = 0.f;
    for (int j = t; j < FFNN_DIM; j += 256) {
        float acc = b2[j];
        for (int k = 0; k < FFNN_DIM; ++k) acc += h1s[k] * w2[k * FFNN_DIM + j];
        partial += fmaxf(acc, 0.f) * w3[j];
    }
    red[t] = partial;
    __syncthreads();
    for (int s = 128; s > 0; s >>= 1) { if (t < s) red[t] += red[t + s]; __syncthreads(); }
    if (t == 0) out[r] = red[0] + b3[0];
}

// ---------------- span embedding: [8192, 2324] ----------------
__global__ void span_emb_kernel(const float* __restrict__ doc, const float* __restrict__ swe,
                                const float* __restrict__ head_s, const int* __restrict__ starts,
                                const int* __restrict__ ends, float* __restrict__ span_emb) {
    int c = blockIdx.x;
    int s = starts[c], e = ends[c];
    int wid = e - s;  // 0..29
    __shared__ float attn[MSW];
    int t = threadIdx.x;
    if (t < 64) {
        int w = t;
        float hsv = -INFINITY;
        if (w < MSW && w <= wid) {
            int j = min(s + w, NUM_WORDS - 1);
            hsv = head_s[j];
        }
        float m = hsv;
        for (int off = 32; off > 0; off >>= 1) m = fmaxf(m, __shfl_down(m, off));
        m = __shfl(m, 0);
        float ex = (w < MSW && w <= wid) ? expf(hsv - m) : 0.f;
        float ssum = ex;
        for (int off = 32; off > 0; off >>= 1) ssum += __shfl_down(ssum, off);
        ssum = __shfl(ssum, 0);
        if (w < MSW) attn[w] = ex / ssum;
    }
    __syncthreads();
    float* out = span_emb + (size_t)c * SPAN_DIM;
    for (int h = t; h < HIDDEN; h += blockDim.x) {
        out[h] = doc[s * HIDDEN + h];
        out[HIDDEN + h] = doc[e * HIDDEN + h];
        float acc = 0.f;
        for (int w = 0; w <= wid; ++w) {
            int j = min(s + w, NUM_WORDS - 1);
            acc += attn[w] * doc[j * HIDDEN + h];
        }
        out[2 * HIDDEN + FEAT + h] = acc;
    }
    if (t < FEAT) out[2 * HIDDEN + t] = swe[wid * FEAT + t];
}

// ---------------- tiled fp32 GEMM: C = relu(A @ B + bias), A[M,K] B[K,N] ----------------
#define TM 64
#define TN 64
#define TKK 16
__global__ __launch_bounds__(256) void gemm_relu(const float* __restrict__ A,
                                                 const float* __restrict__ B,
                                                 const float* __restrict__ bias,
                                                 float* __restrict__ C,
                                                 int M, int N, int K, int do_relu) {
    __shared__ float As[TKK][TM + 4];
    __shared__ float Bs[TKK][TN + 4];
    int t = threadIdx.x;
    int bm = blockIdx.x * TM;
    int bn = blockIdx.y * TN;
    int tx = t & 15, ty = t >> 4;
    float acc[4][4] = {};
    int KT = (K + TKK - 1) / TKK;
    for (int kt = 0; kt < KT; ++kt) {
        int k0 = kt * TKK;
#pragma unroll
        for (int q = 0; q < 4; ++q) {
            int e = q * 256 + t;
            int m = e >> 4, k = e & 15;
            int gk = k0 + k;
            float v = 0.f;
            if (gk < K) v = A[(size_t)(bm + m) * K + gk];
            As[k][m] = v;
        }
#pragma unroll
        for (int q = 0; q < 4; ++q) {
            int e = q * 256 + t;
            int k = e >> 6, n = e & 63;
            int gk = k0 + k, gn = bn + n;
            float v = 0.f;
            if (gk < K && gn < N) v = B[(size_t)gk * N + gn];
            Bs[k][n] = v;
        }
        __syncthreads();
#pragma unroll
        for (int kk = 0; kk < TKK; ++kk) {
            float4 a = *(const float4*)&As[kk][ty * 4];
            float4 b = *(const float4*)&Bs[kk][tx * 4];
            float av[4] = {a.x, a.y, a.z, a.w};
            float bv[4] = {b.x, b.y, b.z, b.w};
#pragma unroll
            for (int i = 0; i < 4; ++i)
#pragma unroll
                for (int j = 0; j < 4; ++j) acc[i][j] += av[i] * bv[j];
        }
        __syncthreads();
    }
#pragma unroll
    for (int i = 0; i < 4; ++i) {
        int gm = bm + ty * 4 + i;
#pragma unroll
        for (int j = 0; j < 4; ++j) {
            int gn = bn + tx * 4 + j;
            if (gn < N) {
                float v = acc[i][j] + bias[gn];
                if (do_relu) v = fmaxf(v, 0.f);
                C[(size_t)gm * N + gn] = v;
            }
        }
    }
}

// ---------------- final scores: h2 @ w3 + b3 + width_scores[e-s] -> d_out[0:8192] ----------------
__global__ void score_kernel(const float* __restrict__ h2, const float* __restrict__ w3,
                             const float* __restrict__ b3, const float* __restrict__ width_s,
                             const int* __restrict__ starts, const int* __restrict__ ends,
                             float* __restrict__ out) {
    int wave = threadIdx.x >> 6, lane = threadIdx.x & 63;
    int c = blockIdx.x * 4 + wave;
    if (c >= NUM_CAND) return;
    const float* row = h2 + (size_t)c * FFNN_DIM;
    float acc = 0.f;
    for (int j = lane; j < FFNN_DIM; j += 64) acc += row[j] * w3[j];
    for (int off = 32; off > 0; off >>= 1) acc += __shfl_down(acc, off);
    if (lane == 0) out[c] = acc + b3[0] + width_s[ends[c] - starts[c]];
}

// ---------------- sort + greedy crossing-NMS + final span-order sort ----------------
__global__ __launch_bounds__(1024) void select_kernel(const float* scores,
                                                      const int* __restrict__ starts,
                                                      const int* __restrict__ ends,
                                                      float* out, int* top_idx_ws) {
    __shared__ unsigned long long keys[NUM_CAND];  // 64 KB, reused as a union after sort
    char* smem = (char*)keys;
    int t = threadIdx.x;

    // build keys: ascending sort == descending score, ties -> ascending idx (stable argsort)
    for (int i = t; i < NUM_CAND; i += 1024) {
        unsigned int b = __float_as_uint(scores[i]);
        unsigned int u = b ^ ((b & 0x80000000u) ? 0xFFFFFFFFu : 0x80000000u);
        unsigned int hi = ~u;
        keys[i] = ((unsigned long long)hi << 32) | (unsigned int)i;
    }
    __syncthreads();

    // bitonic sort 8192 u64 keys
    for (int size = 2; size <= NUM_CAND; size <<= 1) {
        for (int stride = size >> 1; stride > 0; stride >>= 1) {
            for (int i = t; i < NUM_CAND; i += 1024) {
                int ixj = i ^ stride;
                if (ixj > i) {
                    bool up = ((i & size) == 0);
                    unsigned long long a = keys[i], b = keys[ixj];
                    if ((a > b) == up) { keys[i] = b; keys[ixj] = a; }
                }
            }
            __syncthreads();
        }
    }

    // save this thread's 8 sorted idx into registers, then repack LDS union
    int myidx[8];
#pragma unroll
    for (int q = 0; q < 8; ++q) myidx[q] = (int)(keys[t + q * 1024] & 0xFFFFFFFFull);
    __syncthreads();

    unsigned short* ord = (unsigned short*)smem;                    // [8192] @ 0     (16 KB)
    unsigned int* se = (unsigned int*)(smem + 16384);               // [8192] @ 16K   (32 KB)
    volatile short* max_end = (volatile short*)(smem + 49152);      // [2048] @ 48K   (4 KB)
    volatile short* min_start = (volatile short*)(smem + 53248);    // [2048] @ 52K   (4 KB)
    volatile unsigned short* sel = (volatile unsigned short*)(smem + 57344); // [819] (2 KB)
    int* count_sh = (int*)(smem + 59392);

#pragma unroll
    for (int q = 0; q < 8; ++q) {
        int i = t + q * 1024;
        int idx = myidx[q];
        int s = starts[idx], e = ends[idx];
        ord[i] = (unsigned short)idx;
        se[i] = ((unsigned int)s << 16) | (unsigned int)e;
    }
    for (int i = t; i < NUM_WORDS; i += 1024) {
        max_end[i] = (short)-1;
        min_start[i] = (short)NUM_WORDS;
    }
    if (t == 0) *count_sh = 0;
    __syncthreads();

    // greedy NMS on wave 0
    if (t < 64) {
        int count = 0;
        for (int i = 0; i < NUM_CAND; ++i) {
            unsigned int sev = se[i];
            int s = (int)(sev >> 16), e = (int)(sev & 0xFFFFu);
            bool dup = ((int)max_end[s] == e);
            bool cross = false;
            int w = t;
            if (w < MSW) {
                int j = s + w;
                if (j <= e) {  // j <= e < 2048, no clamp needed
                    if (w > 0 && (int)max_end[j] > e) cross = true;
                    if (j < e && (int)min_start[j] < s) cross = true;
                }
            }
            bool crossed = (__ballot(cross) != 0ull);
            bool accept = !dup && !crossed && (count < TOP_NUM);
            if (accept) {
                if (t == 0) {
                    sel[count] = ord[i];
                    if (e > (int)max_end[s]) max_end[s] = (short)e;
                    if (s < (int)min_start[e]) min_start[e] = (short)s;
                }
                ++count;
                if (count == TOP_NUM) break;
            }
        }
        if (t == 0) *count_sh = count;
    }
    __syncthreads();
    int count = *count_sh;

    // final sort of selected spans by (start*2048 + end), pad to 1024 with MAX keys
    unsigned long long* fkeys = (unsigned long long*)(smem + 49152);  // 8 KB, overlays max/min
    {
        unsigned long long k;
        if (t < count) {
            int idx = (int)sel[t];
            unsigned int key32 = (unsigned int)(starts[idx] * NUM_WORDS + ends[idx]);
            k = ((unsigned long long)key32 << 32) | (unsigned int)idx;
        } else {
            k = 0xFFFFFFFFFFFFFFFFull;
        }
        fkeys[t] = k;
    }
    __syncthreads();
    for (int size = 2; size <= 1024; size <<= 1) {
        for (int stride = size >> 1; stride > 0; stride >>= 1) {
            int ixj = t ^ stride;
            if (ixj > t) {
                bool up = ((t & size) == 0);
                unsigned long long a = fkeys[t], b = fkeys[ixj];
                if ((a > b) == up) { fkeys[t] = b; fkeys[ixj] = a; }
            }
            __syncthreads();
        }
    }

    // emit outputs
    for (int i = t; i < TOP_NUM; i += 1024) {
        int fi = (i < count) ? (int)(fkeys[i] & 0xFFFFFFFFull)
                             : (int)(fkeys[0] & 0xFFFFFFFFull);
        out[OUT_TOPIDX + i] = (float)fi;
        out[OUT_TSTART + i] = (float)starts[fi];
        out[OUT_TEND + i] = (float)ends[fi];
        out[OUT_TSCORE + i] = scores[fi];
        top_idx_ws[i] = fi;
    }
}

// ---------------- gather top_span_emb rows into d_out ----------------
__global__ void gather_emb(const float* __restrict__ span_emb, const int* __restrict__ top_idx_ws,
                           float* __restrict__ out) {
    int r = blockIdx.x;
    int idx = top_idx_ws[r];
    const float* src = span_emb + (size_t)idx * SPAN_DIM;
    float* dst = out + OUT_TEMB + (size_t)r * SPAN_DIM;
    for (int h = threadIdx.x; h < SPAN_DIM; h += blockDim.x) dst[h] = src[h];
}

extern "C" void kernel_launch(void* const* d_in, const int* in_sizes, int n_in,
                              void* d_out, int out_size, void* d_ws, size_t ws_size,
                              hipStream_t stream) {
    const float* mention_doc = (const float*)d_in[0];
    const float* span_width_emb = (const float*)d_in[1];
    const float* head_w = (const float*)d_in[2];
    const float* head_b = (const float*)d_in[3];
    const float* m_w1 = (const float*)d_in[4];
    const float* m_b1 = (const float*)d_in[5];
    const float* m_w2 = (const float*)d_in[6];
    const float* m_b2 = (const float*)d_in[7];
    const float* m_w3 = (const float*)d_in[8];
    const float* m_b3 = (const float*)d_in[9];
    const float* width_prior_emb = (const float*)d_in[10];
    const float* w_w1 = (const float*)d_in[11];
    const float* w_b1 = (const float*)d_in[12];
    const float* w_w2 = (const float*)d_in[13];
    const float* w_b2 = (const float*)d_in[14];
    const float* w_w3 = (const float*)d_in[15];
    const float* w_b3 = (const float*)d_in[16];
    const int* cand_starts = (const int*)d_in[17];
    const int* cand_ends = (const int*)d_in[18];

    float* span_emb = (float*)d_ws;                                   // 8192*2324
    float* h1 = span_emb + (size_t)NUM_CAND * SPAN_DIM;               // 8192*1000
    float* h2 = h1 + (size_t)NUM_CAND * FFNN_DIM;                     // 8192*1000
    float* head_s = h2 + (size_t)NUM_CAND * FFNN_DIM;                 // 2048
    float* width_s = head_s + NUM_WORDS;                              // 32
    int* top_idx_ws = (int*)(width_s + 32);                           // 1024

    size_t need = ((size_t)NUM_CAND * SPAN_DIM + 2 * (size_t)NUM_CAND * FFNN_DIM +
                   NUM_WORDS + 32 + 1024) * sizeof(float);
    if (ws_size < need) {
        fprintf(stderr, "kernel_launch: ws too small (%zu < %zu)\n", ws_size, need);
    }

    float* out = (float*)d_out;

    head_kernel<<<NUM_WORDS / 4, 256, 0, stream>>>(mention_doc, head_w, head_b, head_s);
    width_kernel<<<MSW, 256, 0, stream>>>(width_prior_emb, w_w1, w_b1, w_w2, w_b2, w_w3, w_b3,
                                          width_s);
    span_emb_kernel<<<NUM_CAND, 256, 0, stream>>>(mention_doc, span_width_emb, head_s,
                                                  cand_starts, cand_ends, span_emb);
    gemm_relu<<<dim3(NUM_CAND / TM, (FFNN_DIM + TN - 1) / TN), 256, 0, stream>>>(
        span_emb, m_w1, m_b1, h1, NUM_CAND, FFNN_DIM, SPAN_DIM, 1);
    gemm_relu<<<dim3(NUM_CAND / TM, (FFNN_DIM + TN - 1) / TN), 256, 0, stream>>>(
        h1, m_w2, m_b2, h2, NUM_CAND, FFNN_DIM, FFNN_DIM, 1);
    score_kernel<<<NUM_CAND / 4, 256, 0, stream>>>(h2, m_w3, m_b3, width_s, cand_starts,
                                                   cand_ends, out);
    select_kernel<<<1, 1024, 0, stream>>>(out, cand_starts, cand_ends, out, top_idx_ws);
    gather_emb<<<TOP_NUM, 256, 0, stream>>>(span_emb, top_idx_ws, out);
}

// Round 2
// 1928.547 us; speedup vs baseline: 1.5587x; 1.5587x over previous
//
#include <hip/hip_runtime.h>
#include <cstdio>
#include <cmath>

#define NUM_WORDS 2048
#define NUM_CAND 8192
#define HIDDEN 768
#define FEAT 20
#define FFNN_DIM 1000
#define SPAN_DIM 2324
#define TOP_NUM 819
#define MSW 30

// d_out layout (floats): [scores 8192][top_idx 819][top_starts 819][top_ends 819]
//                        [top_span_emb 819*2324][top_scores 819]
#define OUT_TOPIDX   (NUM_CAND)
#define OUT_TSTART   (NUM_CAND + TOP_NUM)
#define OUT_TEND     (NUM_CAND + 2*TOP_NUM)
#define OUT_TEMB     (NUM_CAND + 3*TOP_NUM)
#define OUT_TSCORE   (NUM_CAND + 3*TOP_NUM + TOP_NUM*SPAN_DIM)

// ---------------- head scores: doc @ head_w + head_b  -> [2048] ----------------
__global__ void head_kernel(const float* __restrict__ doc, const float* __restrict__ hw,
                            const float* __restrict__ hb, float* __restrict__ out) {
    int wave = threadIdx.x >> 6, lane = threadIdx.x & 63;
    int row = blockIdx.x * 4 + wave;
    if (row >= NUM_WORDS) return;
    float acc = 0.f;
    for (int h = lane; h < HIDDEN; h += 64) acc += doc[row * HIDDEN + h] * hw[h];
    for (int off = 32; off > 0; off >>= 1) acc += __shfl_down(acc, off);
    if (lane == 0) out[row] = acc + hb[0];
}

// ---------------- width prior ffnn: [30,20] -> [30] ----------------
__global__ void width_kernel(const float* __restrict__ x, const float* __restrict__ w1,
                             const float* __restrict__ b1, const float* __restrict__ w2,
                             const float* __restrict__ b2, const float* __restrict__ w3,
                             const float* __restrict__ b3, float* __restrict__ out) {
    __shared__ float xs[FEAT];
    __shared__ float h1s[FFNN_DIM];
    __shared__ float red[256];
    int r = blockIdx.x, t = threadIdx.x;
    if (t < FEAT) xs[t] = x[r * FEAT + t];
    __syncthreads();
    for (int j = t; j < FFNN_DIM; j += 256) {
        float acc = b1[j];
        for (int k = 0; k < FEAT; ++k) acc += xs[k] * w1[k * FFNN_DIM + j];
        h1s[j] = fmaxf(acc, 0.f);
    }
    __syncthreads();
    float partial = 0.f;
    for (int j = t; j < FFNN_DIM; j += 256) {
        float acc = b2[j];
        for (int k = 0; k < FFNN_DIM; ++k) acc += h1s[k] * w2[k * FFNN_DIM + j];
        partial += fmaxf(acc, 0.f) * w3[j];
    }
    red[t] = partial;
    __syncthreads();
    for (int s = 128; s > 0; s >>= 1) { if (t < s) red[t] += red[t + s]; __syncthreads(); }
    if (t == 0) out[r] = red[0] + b3[0];
}

// ---------------- span embedding: [8192, 2324] ----------------
__global__ void span_emb_kernel(const float* __restrict__ doc, const float* __restrict__ swe,
                                const float* __restrict__ head_s, const int* __restrict__ starts,
                                const int* __restrict__ ends, float* __restrict__ span_emb) {
    int c = blockIdx.x;
    int s = starts[c], e = ends[c];
    int wid = e - s;  // 0..29
    __shared__ float attn[MSW];
    int t = threadIdx.x;
    if (t < 64) {
        int w = t;
        float hsv = -INFINITY;
        if (w < MSW && w <= wid) {
            int j = min(s + w, NUM_WORDS - 1);
            hsv = head_s[j];
        }
        float m = hsv;
        for (int off = 32; off > 0; off >>= 1) m = fmaxf(m, __shfl_down(m, off));
        m = __shfl(m, 0);
        float ex = (w < MSW && w <= wid) ? expf(hsv - m) : 0.f;
        float ssum = ex;
        for (int off = 32; off > 0; off >>= 1) ssum += __shfl_down(ssum, off);
        ssum = __shfl(ssum, 0);
        if (w < MSW) attn[w] = ex / ssum;
    }
    __syncthreads();
    float* out = span_emb + (size_t)c * SPAN_DIM;
    for (int h = t; h < HIDDEN; h += blockDim.x) {
        out[h] = doc[s * HIDDEN + h];
        out[HIDDEN + h] = doc[e * HIDDEN + h];
        float acc = 0.f;
        for (int w = 0; w <= wid; ++w) {
            int j = min(s + w, NUM_WORDS - 1);
            acc += attn[w] * doc[j * HIDDEN + h];
        }
        out[2 * HIDDEN + FEAT + h] = acc;
    }
    if (t < FEAT) out[2 * HIDDEN + t] = swe[wid * FEAT + t];
}

// ---------------- tiled fp32 GEMM: C = relu(A @ B + bias), A[M,K] B[K,N] ----------------
#define TM 64
#define TN 64
#define TKK 16
__global__ __launch_bounds__(256) void gemm_relu(const float* __restrict__ A,
                                                 const float* __restrict__ B,
                                                 const float* __restrict__ bias,
                                                 float* __restrict__ C,
                                                 int M, int N, int K, int do_relu) {
    __shared__ float As[TKK][TM + 4];
    __shared__ float Bs[TKK][TN + 4];
    int t = threadIdx.x;
    int bm = blockIdx.x * TM;
    int bn = blockIdx.y * TN;
    int tx = t & 15, ty = t >> 4;
    float acc[4][4] = {};
    int KT = (K + TKK - 1) / TKK;
    for (int kt = 0; kt < KT; ++kt) {
        int k0 = kt * TKK;
#pragma unroll
        for (int q = 0; q < 4; ++q) {
            int e = q * 256 + t;
            int m = e >> 4, k = e & 15;
            int gk = k0 + k;
            float v = 0.f;
            if (gk < K) v = A[(size_t)(bm + m) * K + gk];
            As[k][m] = v;
        }
#pragma unroll
        for (int q = 0; q < 4; ++q) {
            int e = q * 256 + t;
            int k = e >> 6, n = e & 63;
            int gk = k0 + k, gn = bn + n;
            float v = 0.f;
            if (gk < K && gn < N) v = B[(size_t)gk * N + gn];
            Bs[k][n] = v;
        }
        __syncthreads();
#pragma unroll
        for (int kk = 0; kk < TKK; ++kk) {
            float4 a = *(const float4*)&As[kk][ty * 4];
            float4 b = *(const float4*)&Bs[kk][tx * 4];
            float av[4] = {a.x, a.y, a.z, a.w};
            float bv[4] = {b.x, b.y, b.z, b.w};
#pragma unroll
            for (int i = 0; i < 4; ++i)
#pragma unroll
                for (int j = 0; j < 4; ++j) acc[i][j] += av[i] * bv[j];
        }
        __syncthreads();
    }
#pragma unroll
    for (int i = 0; i < 4; ++i) {
        int gm = bm + ty * 4 + i;
#pragma unroll
        for (int j = 0; j < 4; ++j) {
            int gn = bn + tx * 4 + j;
            if (gn < N) {
                float v = acc[i][j] + bias[gn];
                if (do_relu) v = fmaxf(v, 0.f);
                C[(size_t)gm * N + gn] = v;
            }
        }
    }
}

// ---------------- final scores: h2 @ w3 + b3 + width_scores[e-s] -> d_out[0:8192] ----------------
__global__ void score_kernel(const float* __restrict__ h2, const float* __restrict__ w3,
                             const float* __restrict__ b3, const float* __restrict__ width_s,
                             const int* __restrict__ starts, const int* __restrict__ ends,
                             float* __restrict__ out) {
    int wave = threadIdx.x >> 6, lane = threadIdx.x & 63;
    int c = blockIdx.x * 4 + wave;
    if (c >= NUM_CAND) return;
    const float* row = h2 + (size_t)c * FFNN_DIM;
    float acc = 0.f;
    for (int j = lane; j < FFNN_DIM; j += 64) acc += row[j] * w3[j];
    for (int off = 32; off > 0; off >>= 1) acc += __shfl_down(acc, off);
    if (lane == 0) out[c] = acc + b3[0] + width_s[ends[c] - starts[c]];
}

// ---------------- sort + speculative-chunked greedy crossing-NMS + final sort ----------------
// LDS layout after the big sort (byte offsets into the 64 KB keys[] region):
//   ord    [8192] u16 @ 0      (16 KB)
//   se     [8192] u32 @ 16384  (32 KB)  ((start<<16)|end)
//   packed [2048] u32 @ 49152  ( 8 KB)  (((max_end+1)<<16)|min_start); init (0<<16)|2048
//   sel    [1024] u16 @ 57344  ( 2 KB)
//   count  int    @ 59392
//   fkeys  [1024] u64 @ 49152  ( 8 KB, overlays packed after greedy phase)
__global__ __launch_bounds__(1024) void select_kernel(const float* scores,
                                                      const int* __restrict__ starts,
                                                      const int* __restrict__ ends,
                                                      float* out, int* top_idx_ws) {
    __shared__ unsigned long long keys[NUM_CAND];  // 64 KB union
    char* smem = (char*)keys;
    int t = threadIdx.x;

    // build keys: ascending sort == descending score, ties -> ascending idx (stable argsort)
    for (int i = t; i < NUM_CAND; i += 1024) {
        unsigned int b = __float_as_uint(scores[i]);
        unsigned int u = b ^ ((b & 0x80000000u) ? 0xFFFFFFFFu : 0x80000000u);
        unsigned int hi = ~u;
        keys[i] = ((unsigned long long)hi << 32) | (unsigned int)i;
    }
    __syncthreads();

    // bitonic sort 8192 u64 keys
    for (int size = 2; size <= NUM_CAND; size <<= 1) {
        for (int stride = size >> 1; stride > 0; stride >>= 1) {
            for (int i = t; i < NUM_CAND; i += 1024) {
                int ixj = i ^ stride;
                if (ixj > i) {
                    bool up = ((i & size) == 0);
                    unsigned long long a = keys[i], b = keys[ixj];
                    if ((a > b) == up) { keys[i] = b; keys[ixj] = a; }
                }
            }
            __syncthreads();
        }
    }

    // save this thread's 8 sorted idx into registers, then repack LDS union
    int myidx[8];
#pragma unroll
    for (int q = 0; q < 8; ++q) myidx[q] = (int)(keys[t + q * 1024] & 0xFFFFFFFFull);
    __syncthreads();

    unsigned short* ord_arr = (unsigned short*)smem;                       // @0
    unsigned int* se_arr = (unsigned int*)(smem + 16384);                  // @16K
    volatile unsigned int* packed = (volatile unsigned int*)(smem + 49152);// @48K
    volatile unsigned short* sel = (volatile unsigned short*)(smem + 57344);
    int* count_sh = (int*)(smem + 59392);

#pragma unroll
    for (int q = 0; q < 8; ++q) {
        int i = t + q * 1024;
        int idx = myidx[q];
        int s = starts[idx], e = ends[idx];
        ord_arr[i] = (unsigned short)idx;
        se_arr[i] = ((unsigned int)s << 16) | (unsigned int)e;
    }
    for (int i = t; i < NUM_WORDS; i += 1024) {
        packed[i] = (0u << 16) | (unsigned int)NUM_WORDS;  // max_end=-1, min_start=2048
    }
    if (t == 0) *count_sh = 0;
    __syncthreads();

    // --- speculative chunked greedy NMS on wave 0 ---
    // Per 64-candidate chunk: evaluate all lanes vs chunk-start state with a
    // branch-free unrolled scan, then serially commit accepts via ballot +
    // closed-form incremental fix-up (state changes only at indices sf, ef).
    if (t < 64) {
        int count = 0;
        int i = 0;
        while (i < NUM_CAND && count < TOP_NUM) {
            int c = i + t;
            bool lv = (c < NUM_CAND);
            unsigned int sev = lv ? se_arr[c] : 0u;
            int s = (int)(sev >> 16), e = (int)(sev & 0xFFFFu);
            int ordv = lv ? (int)ord_arr[c] : 0;
            int me = -2;          // running max_end[s] as seen at this lane's turn
            bool crossed = true;
            if (lv) {
                unsigned int p0 = packed[s];
                me = (int)(p0 >> 16) - 1;
                crossed = (s < e) && ((int)(p0 & 0xFFFFu) < s);  // w=0, c2
#pragma unroll
                for (int w = 1; w < MSW; ++w) {
                    int j = s + w;
                    bool in = (j <= e);
                    unsigned int pj = packed[in ? j : s];
                    int mej = (int)(pj >> 16) - 1;
                    int msj = (int)(pj & 0xFFFFu);
                    crossed = crossed || (in && ((mej > e) || ((j < e) && (msj < s))));
                }
            }
            bool spec = lv && !crossed && (me != e);
            unsigned long long window = ~0ull;
            while (true) {
                unsigned long long b = __ballot(spec) & window;
                if (b == 0ull) break;
                int f = __ffsll((unsigned long long)b) - 1;
                int sf = __shfl(s, f), ef = __shfl(e, f), of = __shfl(ordv, f);
                if (t == 0) {
                    sel[count] = (unsigned short)of;
                    unsigned int p = packed[sf];
                    unsigned int new_me = max(p >> 16, (unsigned int)(ef + 1));
                    packed[sf] = (new_me << 16) | (p & 0xFFFFu);
                    unsigned int q = packed[ef];
                    unsigned int new_ms = min(q & 0xFFFFu, (unsigned int)sf);
                    packed[ef] = (q & 0xFFFF0000u) | new_ms;
                }
                count++;
                if (count >= TOP_NUM) break;
                window &= (f >= 63) ? 0ull : (~0ull << (f + 1));
                if (t > f) {
                    if (s == sf) me = max(me, ef);
                    crossed = crossed || ((s < sf) && (sf <= e) && (ef > e))
                                      || ((sf < s) && (s <= ef) && (ef < e));
                    spec = lv && !crossed && (me != e);
                }
            }
            i += 64;
        }
        if (t == 0) *count_sh = count;
    }
    __syncthreads();
    int count = *count_sh;

    // final sort of selected spans by (start*2048 + end), pad to 1024 with MAX keys
    unsigned long long* fkeys = (unsigned long long*)(smem + 49152);  // overlays packed
    {
        unsigned long long k;
        if (t < count) {
            int idx = (int)sel[t];
            unsigned int key32 = (unsigned int)(starts[idx] * NUM_WORDS + ends[idx]);
            k = ((unsigned long long)key32 << 32) | (unsigned int)idx;
        } else {
            k = 0xFFFFFFFFFFFFFFFFull;
        }
        fkeys[t] = k;
    }
    __syncthreads();
    for (int size = 2; size <= 1024; size <<= 1) {
        for (int stride = size >> 1; stride > 0; stride >>= 1) {
            int ixj = t ^ stride;
            if (ixj > t) {
                bool up = ((t & size) == 0);
                unsigned long long a = fkeys[t], b = fkeys[ixj];
                if ((a > b) == up) { fkeys[t] = b; fkeys[ixj] = a; }
            }
            __syncthreads();
        }
    }

    // emit outputs
    for (int i = t; i < TOP_NUM; i += 1024) {
        int fi = (i < count) ? (int)(fkeys[i] & 0xFFFFFFFFull)
                             : (int)(fkeys[0] & 0xFFFFFFFFull);
        out[OUT_TOPIDX + i] = (float)fi;
        out[OUT_TSTART + i] = (float)starts[fi];
        out[OUT_TEND + i] = (float)ends[fi];
        out[OUT_TSCORE + i] = scores[fi];
        top_idx_ws[i] = fi;
    }
}

// ---------------- gather top_span_emb rows into d_out ----------------
__global__ void gather_emb(const float* __restrict__ span_emb, const int* __restrict__ top_idx_ws,
                           float* __restrict__ out) {
    int r = blockIdx.x;
    int idx = top_idx_ws[r];
    const float* src = span_emb + (size_t)idx * SPAN_DIM;
    float* dst = out + OUT_TEMB + (size_t)r * SPAN_DIM;
    for (int h = threadIdx.x; h < SPAN_DIM; h += blockDim.x) dst[h] = src[h];
}

extern "C" void kernel_launch(void* const* d_in, const int* in_sizes, int n_in,
                              void* d_out, int out_size, void* d_ws, size_t ws_size,
                              hipStream_t stream) {
    const float* mention_doc = (const float*)d_in[0];
    const float* span_width_emb = (const float*)d_in[1];
    const float* head_w = (const float*)d_in[2];
    const float* head_b = (const float*)d_in[3];
    const float* m_w1 = (const float*)d_in[4];
    const float* m_b1 = (const float*)d_in[5];
    const float* m_w2 = (const float*)d_in[6];
    const float* m_b2 = (const float*)d_in[7];
    const float* m_w3 = (const float*)d_in[8];
    const float* m_b3 = (const float*)d_in[9];
    const float* width_prior_emb = (const float*)d_in[10];
    const float* w_w1 = (const float*)d_in[11];
    const float* w_b1 = (const float*)d_in[12];
    const float* w_w2 = (const float*)d_in[13];
    const float* w_b2 = (const float*)d_in[14];
    const float* w_w3 = (const float*)d_in[15];
    const float* w_b3 = (const float*)d_in[16];
    const int* cand_starts = (const int*)d_in[17];
    const int* cand_ends = (const int*)d_in[18];

    float* span_emb = (float*)d_ws;                                   // 8192*2324
    float* h1 = span_emb + (size_t)NUM_CAND * SPAN_DIM;               // 8192*1000
    float* h2 = h1 + (size_t)NUM_CAND * FFNN_DIM;                     // 8192*1000
    float* head_s = h2 + (size_t)NUM_CAND * FFNN_DIM;                 // 2048
    float* width_s = head_s + NUM_WORDS;                              // 32
    int* top_idx_ws = (int*)(width_s + 32);                           // 1024

    float* out = (float*)d_out;

    head_kernel<<<NUM_WORDS / 4, 256, 0, stream>>>(mention_doc, head_w, head_b, head_s);
    width_kernel<<<MSW, 256, 0, stream>>>(width_prior_emb, w_w1, w_b1, w_w2, w_b2, w_w3, w_b3,
                                          width_s);
    span_emb_kernel<<<NUM_CAND, 256, 0, stream>>>(mention_doc, span_width_emb, head_s,
                                                  cand_starts, cand_ends, span_emb);
    gemm_relu<<<dim3(NUM_CAND / TM, (FFNN_DIM + TN - 1) / TN), 256, 0, stream>>>(
        span_emb, m_w1, m_b1, h1, NUM_CAND, FFNN_DIM, SPAN_DIM, 1);
    gemm_relu<<<dim3(NUM_CAND / TM, (FFNN_DIM + TN - 1) / TN), 256, 0, stream>>>(
        h1, m_w2, m_b2, h2, NUM_CAND, FFNN_DIM, FFNN_DIM, 1);
    score_kernel<<<NUM_CAND / 4, 256, 0, stream>>>(h2, m_w3, m_b3, width_s, cand_starts,
                                                   cand_ends, out);
    select_kernel<<<1, 1024, 0, stream>>>(out, cand_starts, cand_ends, out, top_idx_ws);
    gather_emb<<<TOP_NUM, 256, 0, stream>>>(span_emb, top_idx_ws, out);
}

// Round 4
// 1216.378 us; speedup vs baseline: 2.4713x; 1.5855x over previous
//
#include <hip/hip_runtime.h>
#include <cstdio>
#include <cmath>

#define NUM_WORDS 2048
#define NUM_CAND 8192
#define HIDDEN 768
#define FEAT 20
#define FFNN_DIM 1000
#define SPAN_DIM 2324
#define TOP_NUM 819
#define MSW 30
#define KP1 2336   // SPAN_DIM padded to x32
#define KP2 1024   // FFNN padded to x32
#define NP 1024    // padded N

// d_out layout (floats): [scores 8192][top_idx 819][top_starts 819][top_ends 819]
//                        [top_span_emb 819*2324][top_scores 819]
#define OUT_TOPIDX   (NUM_CAND)
#define OUT_TSTART   (NUM_CAND + TOP_NUM)
#define OUT_TEND     (NUM_CAND + 2*TOP_NUM)
#define OUT_TEMB     (NUM_CAND + 3*TOP_NUM)
#define OUT_TSCORE   (NUM_CAND + 3*TOP_NUM + TOP_NUM*SPAN_DIM)

typedef short short8 __attribute__((ext_vector_type(8)));
typedef float f32x4 __attribute__((ext_vector_type(4)));

__device__ __forceinline__ unsigned short bf16_rne(float x) {
    unsigned int u = __float_as_uint(x);
    unsigned int r = u + 0x7FFFu + ((u >> 16) & 1u);
    return (unsigned short)(r >> 16);
}
__device__ __forceinline__ float bf16_to_f(unsigned short h) {
    return __uint_as_float(((unsigned int)h) << 16);
}
// 3-way split: v = s0 + s1 + s2 + r, |r| <= 2^-27 |v|
__device__ __forceinline__ void store_split3(unsigned short* p0, unsigned short* p1,
                                             unsigned short* p2, size_t off, float v) {
    unsigned short h0 = bf16_rne(v);
    float r1 = v - bf16_to_f(h0);
    unsigned short h1 = bf16_rne(r1);
    float r2 = r1 - bf16_to_f(h1);
    p0[off] = h0;
    p1[off] = h1;
    p2[off] = bf16_rne(r2);
}

// ---------------- head scores: doc @ head_w + head_b  -> [2048] ----------------
__global__ void head_kernel(const float* __restrict__ doc, const float* __restrict__ hw,
                            const float* __restrict__ hb, float* __restrict__ out) {
    int wave = threadIdx.x >> 6, lane = threadIdx.x & 63;
    int row = blockIdx.x * 4 + wave;
    if (row >= NUM_WORDS) return;
    float acc = 0.f;
    for (int h = lane; h < HIDDEN; h += 64) acc += doc[row * HIDDEN + h] * hw[h];
    for (int off = 32; off > 0; off >>= 1) acc += __shfl_down(acc, off);
    if (lane == 0) out[row] = acc + hb[0];
}

// ---------------- width prior ffnn: [30,20] -> [30] ----------------
__global__ void width_kernel(const float* __restrict__ x, const float* __restrict__ w1,
                             const float* __restrict__ b1, const float* __restrict__ w2,
                             const float* __restrict__ b2, const float* __restrict__ w3,
                             const float* __restrict__ b3, float* __restrict__ out) {
    __shared__ float xs[FEAT];
    __shared__ float h1s[FFNN_DIM];
    __shared__ float red[256];
    int r = blockIdx.x, t = threadIdx.x;
    if (t < FEAT) xs[t] = x[r * FEAT + t];
    __syncthreads();
    for (int j = t; j < FFNN_DIM; j += 256) {
        float acc = b1[j];
        for (int k = 0; k < FEAT; ++k) acc += xs[k] * w1[k * FFNN_DIM + j];
        h1s[j] = fmaxf(acc, 0.f);
    }
    __syncthreads();
    float partial = 0.f;
    for (int j = t; j < FFNN_DIM; j += 256) {
        float acc = b2[j];
        for (int k = 0; k < FFNN_DIM; ++k) acc += h1s[k] * w2[k * FFNN_DIM + j];
        partial += fmaxf(acc, 0.f) * w3[j];
    }
    red[t] = partial;
    __syncthreads();
    for (int s = 128; s > 0; s >>= 1) { if (t < s) red[t] += red[t + s]; __syncthreads(); }
    if (t == 0) out[r] = red[0] + b3[0];
}

// ---------------- weight convert+transpose: w[K][N] -> 3-split [NP][Kp] (zero-padded) ------
__global__ void convert_wt(const float* __restrict__ w, int K, int N, int Kp,
                           unsigned short* __restrict__ q0, unsigned short* __restrict__ q1,
                           unsigned short* __restrict__ q2) {
    int n = blockIdx.y;
    int k = blockIdx.x * blockDim.x + threadIdx.x;
    if (k >= Kp) return;
    float v = (k < K && n < N) ? w[(size_t)k * N + n] : 0.f;
    store_split3(q0, q1, q2, (size_t)n * Kp + k, v);
}

// ---------------- span embedding -> A 3-split bf16 [8192][2336] ----------------
__global__ void span_emb_kernel(const float* __restrict__ doc, const float* __restrict__ swe,
                                const float* __restrict__ head_s, const int* __restrict__ starts,
                                const int* __restrict__ ends,
                                unsigned short* __restrict__ A0, unsigned short* __restrict__ A1,
                                unsigned short* __restrict__ A2) {
    int c = blockIdx.x;
    int s = starts[c], e = ends[c];
    int wid = e - s;  // 0..29
    __shared__ float attn[MSW];
    int t = threadIdx.x;
    if (t < 64) {
        int w = t;
        float hsv = -INFINITY;
        if (w < MSW && w <= wid) hsv = head_s[s + w];
        float m = hsv;
        for (int off = 32; off > 0; off >>= 1) m = fmaxf(m, __shfl_down(m, off));
        m = __shfl(m, 0);
        float ex = (w < MSW && w <= wid) ? expf(hsv - m) : 0.f;
        float ssum = ex;
        for (int off = 32; off > 0; off >>= 1) ssum += __shfl_down(ssum, off);
        ssum = __shfl(ssum, 0);
        if (w < MSW) attn[w] = ex / ssum;
    }
    __syncthreads();
    size_t base = (size_t)c * KP1;
    for (int h = t; h < HIDDEN; h += blockDim.x) {
        float v0 = doc[s * HIDDEN + h];
        float v1 = doc[e * HIDDEN + h];
        float accv = 0.f;
        for (int w = 0; w <= wid; ++w) accv += attn[w] * doc[(s + w) * HIDDEN + h];
        store_split3(A0, A1, A2, base + h, v0);
        store_split3(A0, A1, A2, base + HIDDEN + h, v1);
        store_split3(A0, A1, A2, base + 2 * HIDDEN + FEAT + h, accv);
    }
    if (t < FEAT) store_split3(A0, A1, A2, base + 2 * HIDDEN + t, swe[wid * FEAT + t]);
    if (t < KP1 - SPAN_DIM) {
        A0[base + SPAN_DIM + t] = 0; A1[base + SPAN_DIM + t] = 0; A2[base + SPAN_DIM + t] = 0;
    }
}

// ---------------- 3-split 6-product MFMA GEMM ----------------
// C[m][n] = relu(sum_k A[m][k]*B[n][k] + bias[n]); A = [8192][Kp] x3, B = [1024][Kp] x3.
// Products kept: a0b0, a0b1, a1b0, a1b1, a0b2, a2b0 (residual <= ~2^-26 per term).
// mode 0: store C as 3-split bf16 [8192][NP].
// mode 1: partials[m*16 + pid] = sum over this block-wave's 64 n of relu(...)*w3[n]
//         (pid = n_block*2 + wn_half; deterministic — no atomics).
__global__ __launch_bounds__(256, 2) void gemm6(
    const unsigned short* __restrict__ A0, const unsigned short* __restrict__ A1,
    const unsigned short* __restrict__ A2,
    const unsigned short* __restrict__ B0, const unsigned short* __restrict__ B1,
    const unsigned short* __restrict__ B2,
    const float* __restrict__ bias, int nreal, int Kp, int mode,
    unsigned short* __restrict__ C0, unsigned short* __restrict__ C1,
    unsigned short* __restrict__ C2,
    const float* __restrict__ w3, float* __restrict__ partials) {
    __shared__ unsigned short As0[128 * 40], As1[128 * 40], As2[128 * 40];
    __shared__ unsigned short Bs0[128 * 40], Bs1[128 * 40], Bs2[128 * 40];
    int t = threadIdx.x;
    int bid = blockIdx.x;
    // 8x8 supertile swizzle: 8 consecutive m-blocks share B in L2/L3
    int sm = bid >> 6, idx = bid & 63;
    int bm = ((sm << 3) + (idx & 7)) << 7;
    int bn = (idx >> 3) << 7;
    int lane = t & 63, wv = t >> 6;
    int wm = (wv >> 1) * 64, wn = (wv & 1) * 64;
    int lr = lane & 15, qq = lane >> 4;

    f32x4 acc[4][4] = {};

    for (int k0 = 0; k0 < Kp; k0 += 32) {
#pragma unroll
        for (int qi = 0; qi < 2; ++qi) {
            int u = qi * 256 + t;
            int m = u >> 2, blk = u & 3;
            size_t ga = (size_t)(bm + m) * Kp + k0 + blk * 8;
            size_t gb = (size_t)(bn + m) * Kp + k0 + blk * 8;
            uint4 va0 = *(const uint4*)(A0 + ga);
            uint4 va1 = *(const uint4*)(A1 + ga);
            uint4 va2 = *(const uint4*)(A2 + ga);
            uint4 vb0 = *(const uint4*)(B0 + gb);
            uint4 vb1 = *(const uint4*)(B1 + gb);
            uint4 vb2 = *(const uint4*)(B2 + gb);
            int la = m * 40 + blk * 8;
            *(uint4*)&As0[la] = va0;
            *(uint4*)&As1[la] = va1;
            *(uint4*)&As2[la] = va2;
            *(uint4*)&Bs0[la] = vb0;
            *(uint4*)&Bs1[la] = vb1;
            *(uint4*)&Bs2[la] = vb2;
        }
        __syncthreads();
        short8 a0[4], a1[4], a2[4];
#pragma unroll
        for (int i = 0; i < 4; ++i) {
            int ra = (wm + i * 16 + lr) * 40 + qq * 8;
            a0[i] = *(const short8*)&As0[ra];
            a1[i] = *(const short8*)&As1[ra];
            a2[i] = *(const short8*)&As2[ra];
        }
#pragma unroll
        for (int j = 0; j < 4; ++j) {
            int rb = (wn + j * 16 + lr) * 40 + qq * 8;
            short8 b0 = *(const short8*)&Bs0[rb];
            short8 b1 = *(const short8*)&Bs1[rb];
            short8 b2 = *(const short8*)&Bs2[rb];
#pragma unroll
            for (int i = 0; i < 4; ++i) {
                acc[i][j] = __builtin_amdgcn_mfma_f32_16x16x32_bf16(a2[i], b0, acc[i][j], 0, 0, 0);
                acc[i][j] = __builtin_amdgcn_mfma_f32_16x16x32_bf16(a0[i], b2, acc[i][j], 0, 0, 0);
                acc[i][j] = __builtin_amdgcn_mfma_f32_16x16x32_bf16(a1[i], b1, acc[i][j], 0, 0, 0);
                acc[i][j] = __builtin_amdgcn_mfma_f32_16x16x32_bf16(a1[i], b0, acc[i][j], 0, 0, 0);
                acc[i][j] = __builtin_amdgcn_mfma_f32_16x16x32_bf16(a0[i], b1, acc[i][j], 0, 0, 0);
                acc[i][j] = __builtin_amdgcn_mfma_f32_16x16x32_bf16(a0[i], b0, acc[i][j], 0, 0, 0);
            }
        }
        __syncthreads();
    }

    if (mode == 0) {
#pragma unroll
        for (int i = 0; i < 4; ++i)
#pragma unroll
            for (int j = 0; j < 4; ++j)
#pragma unroll
                for (int r = 0; r < 4; ++r) {
                    int m = bm + wm + i * 16 + qq * 4 + r;   // C/D: row = quad*4+reg
                    int n = bn + wn + j * 16 + lr;           //      col = lane&15
                    float v = acc[i][j][r] + (n < nreal ? bias[n] : 0.f);
                    v = fmaxf(v, 0.f);
                    store_split3(C0, C1, C2, (size_t)m * NP + n, v);
                }
    } else {
        int pid = ((bn >> 7) << 1) | (wn >> 6);  // 0..15
#pragma unroll
        for (int i = 0; i < 4; ++i)
#pragma unroll
            for (int r = 0; r < 4; ++r) {
                float p = 0.f;
#pragma unroll
                for (int j = 0; j < 4; ++j) {
                    int n = bn + wn + j * 16 + lr;
                    float v = acc[i][j][r] + (n < nreal ? bias[n] : 0.f);
                    v = fmaxf(v, 0.f);
                    p += v * (n < nreal ? w3[n] : 0.f);
                }
                p += __shfl_xor(p, 1);
                p += __shfl_xor(p, 2);
                p += __shfl_xor(p, 4);
                p += __shfl_xor(p, 8);
                if (lr == 0) {
                    int m = bm + wm + i * 16 + qq * 4 + r;
                    partials[(size_t)m * 16 + pid] = p;
                }
            }
    }
}

// ---------------- deterministic score finalize ----------------
__global__ void score_final(const float* __restrict__ partials, const float* __restrict__ b3,
                            const float* __restrict__ width_s, const int* __restrict__ starts,
                            const int* __restrict__ ends, float* __restrict__ out) {
    int c = blockIdx.x * 256 + threadIdx.x;
    if (c >= NUM_CAND) return;
    float s = b3[0] + width_s[ends[c] - starts[c]];
#pragma unroll
    for (int p = 0; p < 16; ++p) s += partials[(size_t)c * 16 + p];
    out[c] = s;
}

// ---------------- sort + speculative-chunked greedy crossing-NMS + final sort ----------------
__global__ __launch_bounds__(1024) void select_kernel(const float* scores,
                                                      const int* __restrict__ starts,
                                                      const int* __restrict__ ends,
                                                      float* out, int* top_idx_ws) {
    __shared__ unsigned long long keys[NUM_CAND];  // 64 KB union
    char* smem = (char*)keys;
    int t = threadIdx.x;

    for (int i = t; i < NUM_CAND; i += 1024) {
        unsigned int b = __float_as_uint(scores[i]);
        unsigned int u = b ^ ((b & 0x80000000u) ? 0xFFFFFFFFu : 0x80000000u);
        unsigned int hi = ~u;
        keys[i] = ((unsigned long long)hi << 32) | (unsigned int)i;
    }
    __syncthreads();

    for (int size = 2; size <= NUM_CAND; size <<= 1) {
        for (int stride = size >> 1; stride > 0; stride >>= 1) {
            for (int i = t; i < NUM_CAND; i += 1024) {
                int ixj = i ^ stride;
                if (ixj > i) {
                    bool up = ((i & size) == 0);
                    unsigned long long a = keys[i], b = keys[ixj];
                    if ((a > b) == up) { keys[i] = b; keys[ixj] = a; }
                }
            }
            __syncthreads();
        }
    }

    int myidx[8];
#pragma unroll
    for (int q = 0; q < 8; ++q) myidx[q] = (int)(keys[t + q * 1024] & 0xFFFFFFFFull);
    __syncthreads();

    unsigned short* ord_arr = (unsigned short*)smem;
    unsigned int* se_arr = (unsigned int*)(smem + 16384);
    volatile unsigned int* packed = (volatile unsigned int*)(smem + 49152);
    volatile unsigned short* sel = (volatile unsigned short*)(smem + 57344);
    int* count_sh = (int*)(smem + 59392);

#pragma unroll
    for (int q = 0; q < 8; ++q) {
        int i = t + q * 1024;
        int idx = myidx[q];
        int s = starts[idx], e = ends[idx];
        ord_arr[i] = (unsigned short)idx;
        se_arr[i] = ((unsigned int)s << 16) | (unsigned int)e;
    }
    for (int i = t; i < NUM_WORDS; i += 1024) {
        packed[i] = (0u << 16) | (unsigned int)NUM_WORDS;
    }
    if (t == 0) *count_sh = 0;
    __syncthreads();

    if (t < 64) {
        int count = 0;
        int i = 0;
        while (i < NUM_CAND && count < TOP_NUM) {
            int c = i + t;
            bool lv = (c < NUM_CAND);
            unsigned int sev = lv ? se_arr[c] : 0u;
            int s = (int)(sev >> 16), e = (int)(sev & 0xFFFFu);
            int ordv = lv ? (int)ord_arr[c] : 0;
            int me = -2;
            bool crossed = true;
            if (lv) {
                unsigned int p0 = packed[s];
                me = (int)(p0 >> 16) - 1;
                crossed = (s < e) && ((int)(p0 & 0xFFFFu) < s);
#pragma unroll
                for (int w = 1; w < MSW; ++w) {
                    int j = s + w;
                    bool in = (j <= e);
                    unsigned int pj = packed[in ? j : s];
                    int mej = (int)(pj >> 16) - 1;
                    int msj = (int)(pj & 0xFFFFu);
                    crossed = crossed || (in && ((mej > e) || ((j < e) && (msj < s))));
                }
            }
            bool spec = lv && !crossed && (me != e);
            unsigned long long window = ~0ull;
            while (true) {
                unsigned long long b = __ballot(spec) & window;
                if (b == 0ull) break;
                int f = __ffsll((unsigned long long)b) - 1;
                int sf = __shfl(s, f), ef = __shfl(e, f), of = __shfl(ordv, f);
                if (t == 0) {
                    sel[count] = (unsigned short)of;
                    unsigned int p = packed[sf];
                    unsigned int new_me = max(p >> 16, (unsigned int)(ef + 1));
                    packed[sf] = (new_me << 16) | (p & 0xFFFFu);
                    unsigned int q = packed[ef];
                    unsigned int new_ms = min(q & 0xFFFFu, (unsigned int)sf);
                    packed[ef] = (q & 0xFFFF0000u) | new_ms;
                }
                count++;
                if (count >= TOP_NUM) break;
                window &= (f >= 63) ? 0ull : (~0ull << (f + 1));
                if (t > f) {
                    if (s == sf) me = max(me, ef);
                    crossed = crossed || ((s < sf) && (sf <= e) && (ef > e))
                                      || ((sf < s) && (s <= ef) && (ef < e));
                    spec = lv && !crossed && (me != e);
                }
            }
            i += 64;
        }
        if (t == 0) *count_sh = count;
    }
    __syncthreads();
    int count = *count_sh;

    unsigned long long* fkeys = (unsigned long long*)(smem + 49152);
    {
        unsigned long long k;
        if (t < count) {
            int idx = (int)sel[t];
            unsigned int key32 = (unsigned int)(starts[idx] * NUM_WORDS + ends[idx]);
            k = ((unsigned long long)key32 << 32) | (unsigned int)idx;
        } else {
            k = 0xFFFFFFFFFFFFFFFFull;
        }
        fkeys[t] = k;
    }
    __syncthreads();
    for (int size = 2; size <= 1024; size <<= 1) {
        for (int stride = size >> 1; stride > 0; stride >>= 1) {
            int ixj = t ^ stride;
            if (ixj > t) {
                bool up = ((t & size) == 0);
                unsigned long long a = fkeys[t], b = fkeys[ixj];
                if ((a > b) == up) { fkeys[t] = b; fkeys[ixj] = a; }
            }
            __syncthreads();
        }
    }

    for (int i = t; i < TOP_NUM; i += 1024) {
        int fi = (i < count) ? (int)(fkeys[i] & 0xFFFFFFFFull)
                             : (int)(fkeys[0] & 0xFFFFFFFFull);
        out[OUT_TOPIDX + i] = (float)fi;
        out[OUT_TSTART + i] = (float)starts[fi];
        out[OUT_TEND + i] = (float)ends[fi];
        out[OUT_TSCORE + i] = scores[fi];
        top_idx_ws[i] = fi;
    }
}

// ---------------- gather top_span_emb rows (reconstruct fp32 = a0+a1+a2) ----------------
__global__ void gather_emb(const unsigned short* __restrict__ A0,
                           const unsigned short* __restrict__ A1,
                           const unsigned short* __restrict__ A2,
                           const int* __restrict__ top_idx_ws, float* __restrict__ out) {
    int r = blockIdx.x;
    int idx = top_idx_ws[r];
    const unsigned short* s0 = A0 + (size_t)idx * KP1;
    const unsigned short* s1 = A1 + (size_t)idx * KP1;
    const unsigned short* s2 = A2 + (size_t)idx * KP1;
    float* dst = out + OUT_TEMB + (size_t)r * SPAN_DIM;
    for (int h = threadIdx.x; h < SPAN_DIM; h += blockDim.x)
        dst[h] = bf16_to_f(s0[h]) + bf16_to_f(s1[h]) + bf16_to_f(s2[h]);
}

extern "C" void kernel_launch(void* const* d_in, const int* in_sizes, int n_in,
                              void* d_out, int out_size, void* d_ws, size_t ws_size,
                              hipStream_t stream) {
    const float* mention_doc = (const float*)d_in[0];
    const float* span_width_emb = (const float*)d_in[1];
    const float* head_w = (const float*)d_in[2];
    const float* head_b = (const float*)d_in[3];
    const float* m_w1 = (const float*)d_in[4];
    const float* m_b1 = (const float*)d_in[5];
    const float* m_w2 = (const float*)d_in[6];
    const float* m_b2 = (const float*)d_in[7];
    const float* m_w3 = (const float*)d_in[8];
    const float* m_b3 = (const float*)d_in[9];
    const float* width_prior_emb = (const float*)d_in[10];
    const float* w_w1 = (const float*)d_in[11];
    const float* w_b1 = (const float*)d_in[12];
    const float* w_w2 = (const float*)d_in[13];
    const float* w_b2 = (const float*)d_in[14];
    const float* w_w3 = (const float*)d_in[15];
    const float* w_b3 = (const float*)d_in[16];
    const int* cand_starts = (const int*)d_in[17];
    const int* cand_ends = (const int*)d_in[18];

    char* w = (char*)d_ws;
    const size_t szA = (size_t)NUM_CAND * KP1 * 2;   // 38.27 MB each
    const size_t szH = (size_t)NUM_CAND * NP * 2;    // 16.78 MB each
    const size_t szW1 = (size_t)NP * KP1 * 2;        // 4.78 MB each
    const size_t szW2 = (size_t)NP * KP2 * 2;        // 2.10 MB each
    unsigned short* A0 = (unsigned short*)w;
    unsigned short* A1 = (unsigned short*)(w + szA);
    unsigned short* A2 = (unsigned short*)(w + 2 * szA);
    char* p = w + 3 * szA;
    unsigned short* h0 = (unsigned short*)p;
    unsigned short* h1 = (unsigned short*)(p + szH);
    unsigned short* h2 = (unsigned short*)(p + 2 * szH);
    p += 3 * szH;
    unsigned short* w1t0 = (unsigned short*)p;
    unsigned short* w1t1 = (unsigned short*)(p + szW1);
    unsigned short* w1t2 = (unsigned short*)(p + 2 * szW1);
    p += 3 * szW1;
    unsigned short* w2t0 = (unsigned short*)p;
    unsigned short* w2t1 = (unsigned short*)(p + szW2);
    unsigned short* w2t2 = (unsigned short*)(p + 2 * szW2);
    p += 3 * szW2;
    float* partials = (float*)p;                    // 8192*16 floats
    p += (size_t)NUM_CAND * 16 * 4;
    float* head_s = (float*)p;                      // 2048 floats
    float* width_s = (float*)(p + 8192);            // 32 floats
    int* top_idx_ws = (int*)(p + 8192 + 128);       // 1024 ints

    size_t need = (size_t)(p - w) + 8192 + 128 + 4096;
    if (ws_size < need) {
        fprintf(stderr, "kernel_launch: ws too small (%zu < %zu)\n", ws_size, need);
    }

    float* out = (float*)d_out;

    head_kernel<<<NUM_WORDS / 4, 256, 0, stream>>>(mention_doc, head_w, head_b, head_s);
    width_kernel<<<MSW, 256, 0, stream>>>(width_prior_emb, w_w1, w_b1, w_w2, w_b2, w_w3, w_b3,
                                          width_s);
    convert_wt<<<dim3((KP1 + 255) / 256, NP), 256, 0, stream>>>(m_w1, SPAN_DIM, FFNN_DIM, KP1,
                                                                w1t0, w1t1, w1t2);
    convert_wt<<<dim3((KP2 + 255) / 256, NP), 256, 0, stream>>>(m_w2, FFNN_DIM, FFNN_DIM, KP2,
                                                                w2t0, w2t1, w2t2);
    span_emb_kernel<<<NUM_CAND, 256, 0, stream>>>(mention_doc, span_width_emb, head_s,
                                                  cand_starts, cand_ends, A0, A1, A2);
    gemm6<<<512, 256, 0, stream>>>(A0, A1, A2, w1t0, w1t1, w1t2, m_b1, FFNN_DIM, KP1, 0,
                                   h0, h1, h2, nullptr, nullptr);
    gemm6<<<512, 256, 0, stream>>>(h0, h1, h2, w2t0, w2t1, w2t2, m_b2, FFNN_DIM, KP2, 1,
                                   nullptr, nullptr, nullptr, m_w3, partials);
    score_final<<<NUM_CAND / 256, 256, 0, stream>>>(partials, m_b3, width_s, cand_starts,
                                                    cand_ends, out);
    select_kernel<<<1, 1024, 0, stream>>>(out, cand_starts, cand_ends, out, top_idx_ws);
    gather_emb<<<TOP_NUM, 256, 0, stream>>>(A0, A1, A2, top_idx_ws, out);
}

// Round 5
// 1099.442 us; speedup vs baseline: 2.7341x; 1.1064x over previous
//
#include <hip/hip_runtime.h>
#include <cstdio>
#include <cmath>

#define NUM_WORDS 2048
#define NUM_CAND 8192
#define HIDDEN 768
#define FEAT 20
#define FFNN_DIM 1000
#define SPAN_DIM 2324
#define TOP_NUM 819
#define MSW 30
#define KP1 2336   // SPAN_DIM padded to x32
#define KP2 1024   // FFNN padded to x32
#define NP 1024    // padded N

// d_out layout (floats): [scores 8192][top_idx 819][top_starts 819][top_ends 819]
//                        [top_span_emb 819*2324][top_scores 819]
#define OUT_TOPIDX   (NUM_CAND)
#define OUT_TSTART   (NUM_CAND + TOP_NUM)
#define OUT_TEND     (NUM_CAND + 2*TOP_NUM)
#define OUT_TEMB     (NUM_CAND + 3*TOP_NUM)
#define OUT_TSCORE   (NUM_CAND + 3*TOP_NUM + TOP_NUM*SPAN_DIM)

typedef short short8 __attribute__((ext_vector_type(8)));
typedef float f32x4 __attribute__((ext_vector_type(4)));

__device__ __forceinline__ unsigned short bf16_rne(float x) {
    unsigned int u = __float_as_uint(x);
    unsigned int r = u + 0x7FFFu + ((u >> 16) & 1u);
    return (unsigned short)(r >> 16);
}
__device__ __forceinline__ float bf16_to_f(unsigned short h) {
    return __uint_as_float(((unsigned int)h) << 16);
}
// 3-way split: v = s0 + s1 + s2 + r, |r| <= 2^-27 |v|
__device__ __forceinline__ void store_split3(unsigned short* p0, unsigned short* p1,
                                             unsigned short* p2, size_t off, float v) {
    unsigned short h0 = bf16_rne(v);
    float r1 = v - bf16_to_f(h0);
    unsigned short h1 = bf16_rne(r1);
    float r2 = r1 - bf16_to_f(h1);
    p0[off] = h0;
    p1[off] = h1;
    p2[off] = bf16_rne(r2);
}

// ---------------- head scores: doc @ head_w + head_b  -> [2048] ----------------
__global__ void head_kernel(const float* __restrict__ doc, const float* __restrict__ hw,
                            const float* __restrict__ hb, float* __restrict__ out) {
    int wave = threadIdx.x >> 6, lane = threadIdx.x & 63;
    int row = blockIdx.x * 4 + wave;
    if (row >= NUM_WORDS) return;
    float acc = 0.f;
    for (int h = lane; h < HIDDEN; h += 64) acc += doc[row * HIDDEN + h] * hw[h];
    for (int off = 32; off > 0; off >>= 1) acc += __shfl_down(acc, off);
    if (lane == 0) out[row] = acc + hb[0];
}

// ---------------- width prior ffnn: [30,20] -> [30] ----------------
__global__ void width_kernel(const float* __restrict__ x, const float* __restrict__ w1,
                             const float* __restrict__ b1, const float* __restrict__ w2,
                             const float* __restrict__ b2, const float* __restrict__ w3,
                             const float* __restrict__ b3, float* __restrict__ out) {
    __shared__ float xs[FEAT];
    __shared__ float h1s[FFNN_DIM];
    __shared__ float red[256];
    int r = blockIdx.x, t = threadIdx.x;
    if (t < FEAT) xs[t] = x[r * FEAT + t];
    __syncthreads();
    for (int j = t; j < FFNN_DIM; j += 256) {
        float acc = b1[j];
        for (int k = 0; k < FEAT; ++k) acc += xs[k] * w1[k * FFNN_DIM + j];
        h1s[j] = fmaxf(acc, 0.f);
    }
    __syncthreads();
    float partial = 0.f;
    for (int j = t; j < FFNN_DIM; j += 256) {
        float acc = b2[j];
        for (int k = 0; k < FFNN_DIM; ++k) acc += h1s[k] * w2[k * FFNN_DIM + j];
        partial += fmaxf(acc, 0.f) * w3[j];
    }
    red[t] = partial;
    __syncthreads();
    for (int s = 128; s > 0; s >>= 1) { if (t < s) red[t] += red[t + s]; __syncthreads(); }
    if (t == 0) out[r] = red[0] + b3[0];
}

// ---------------- weight convert+transpose: w[K][N] -> 3-split [NP][Kp] (zero-padded) ------
__global__ void convert_wt(const float* __restrict__ w, int K, int N, int Kp,
                           unsigned short* __restrict__ q0, unsigned short* __restrict__ q1,
                           unsigned short* __restrict__ q2) {
    int n = blockIdx.y;
    int k = blockIdx.x * blockDim.x + threadIdx.x;
    if (k >= Kp) return;
    float v = (k < K && n < N) ? w[(size_t)k * N + n] : 0.f;
    store_split3(q0, q1, q2, (size_t)n * Kp + k, v);
}

// ---------------- span embedding -> A 3-split bf16 [8192][2336] ----------------
__global__ void span_emb_kernel(const float* __restrict__ doc, const float* __restrict__ swe,
                                const float* __restrict__ head_s, const int* __restrict__ starts,
                                const int* __restrict__ ends,
                                unsigned short* __restrict__ A0, unsigned short* __restrict__ A1,
                                unsigned short* __restrict__ A2) {
    int c = blockIdx.x;
    int s = starts[c], e = ends[c];
    int wid = e - s;  // 0..29
    __shared__ float attn[MSW];
    int t = threadIdx.x;
    if (t < 64) {
        int w = t;
        float hsv = -INFINITY;
        if (w < MSW && w <= wid) hsv = head_s[s + w];
        float m = hsv;
        for (int off = 32; off > 0; off >>= 1) m = fmaxf(m, __shfl_down(m, off));
        m = __shfl(m, 0);
        float ex = (w < MSW && w <= wid) ? expf(hsv - m) : 0.f;
        float ssum = ex;
        for (int off = 32; off > 0; off >>= 1) ssum += __shfl_down(ssum, off);
        ssum = __shfl(ssum, 0);
        if (w < MSW) attn[w] = ex / ssum;
    }
    __syncthreads();
    size_t base = (size_t)c * KP1;
    for (int h = t; h < HIDDEN; h += blockDim.x) {
        float v0 = doc[s * HIDDEN + h];
        float v1 = doc[e * HIDDEN + h];
        float accv = 0.f;
        for (int w = 0; w <= wid; ++w) accv += attn[w] * doc[(s + w) * HIDDEN + h];
        store_split3(A0, A1, A2, base + h, v0);
        store_split3(A0, A1, A2, base + HIDDEN + h, v1);
        store_split3(A0, A1, A2, base + 2 * HIDDEN + FEAT + h, accv);
    }
    if (t < FEAT) store_split3(A0, A1, A2, base + 2 * HIDDEN + t, swe[wid * FEAT + t]);
    if (t < KP1 - SPAN_DIM) {
        A0[base + SPAN_DIM + t] = 0; A1[base + SPAN_DIM + t] = 0; A2[base + SPAN_DIM + t] = 0;
    }
}

// ---------------- 3-split 6-product MFMA GEMM ----------------
// C[m][n] = relu(sum_k A[m][k]*B[n][k] + bias[n]); A = [8192][Kp] x3, B = [1024][Kp] x3.
// Products kept: a0b0, a0b1, a1b0, a1b1, a0b2, a2b0 (residual <= ~2^-26 per term).
// mode 0: store C as 3-split bf16 [8192][NP].
// mode 1: partials[m*16 + pid] = sum over this block-wave's 64 n of relu(...)*w3[n]
//         (pid = n_block*2 + wn_half; deterministic — no atomics).
__global__ __launch_bounds__(256, 2) void gemm6(
    const unsigned short* __restrict__ A0, const unsigned short* __restrict__ A1,
    const unsigned short* __restrict__ A2,
    const unsigned short* __restrict__ B0, const unsigned short* __restrict__ B1,
    const unsigned short* __restrict__ B2,
    const float* __restrict__ bias, int nreal, int Kp, int mode,
    unsigned short* __restrict__ C0, unsigned short* __restrict__ C1,
    unsigned short* __restrict__ C2,
    const float* __restrict__ w3, float* __restrict__ partials) {
    __shared__ unsigned short As0[128 * 40], As1[128 * 40], As2[128 * 40];
    __shared__ unsigned short Bs0[128 * 40], Bs1[128 * 40], Bs2[128 * 40];
    int t = threadIdx.x;
    int bid = blockIdx.x;
    // 8x8 supertile swizzle: 8 consecutive m-blocks share B in L2/L3
    int sm = bid >> 6, idx = bid & 63;
    int bm = ((sm << 3) + (idx & 7)) << 7;
    int bn = (idx >> 3) << 7;
    int lane = t & 63, wv = t >> 6;
    int wm = (wv >> 1) * 64, wn = (wv & 1) * 64;
    int lr = lane & 15, qq = lane >> 4;

    f32x4 acc[4][4] = {};

    for (int k0 = 0; k0 < Kp; k0 += 32) {
#pragma unroll
        for (int qi = 0; qi < 2; ++qi) {
            int u = qi * 256 + t;
            int m = u >> 2, blk = u & 3;
            size_t ga = (size_t)(bm + m) * Kp + k0 + blk * 8;
            size_t gb = (size_t)(bn + m) * Kp + k0 + blk * 8;
            uint4 va0 = *(const uint4*)(A0 + ga);
            uint4 va1 = *(const uint4*)(A1 + ga);
            uint4 va2 = *(const uint4*)(A2 + ga);
            uint4 vb0 = *(const uint4*)(B0 + gb);
            uint4 vb1 = *(const uint4*)(B1 + gb);
            uint4 vb2 = *(const uint4*)(B2 + gb);
            int la = m * 40 + blk * 8;
            *(uint4*)&As0[la] = va0;
            *(uint4*)&As1[la] = va1;
            *(uint4*)&As2[la] = va2;
            *(uint4*)&Bs0[la] = vb0;
            *(uint4*)&Bs1[la] = vb1;
            *(uint4*)&Bs2[la] = vb2;
        }
        __syncthreads();
        short8 a0[4], a1[4], a2[4];
#pragma unroll
        for (int i = 0; i < 4; ++i) {
            int ra = (wm + i * 16 + lr) * 40 + qq * 8;
            a0[i] = *(const short8*)&As0[ra];
            a1[i] = *(const short8*)&As1[ra];
            a2[i] = *(const short8*)&As2[ra];
        }
#pragma unroll
        for (int j = 0; j < 4; ++j) {
            int rb = (wn + j * 16 + lr) * 40 + qq * 8;
            short8 b0 = *(const short8*)&Bs0[rb];
            short8 b1 = *(const short8*)&Bs1[rb];
            short8 b2 = *(const short8*)&Bs2[rb];
#pragma unroll
            for (int i = 0; i < 4; ++i) {
                acc[i][j] = __builtin_amdgcn_mfma_f32_16x16x32_bf16(a2[i], b0, acc[i][j], 0, 0, 0);
                acc[i][j] = __builtin_amdgcn_mfma_f32_16x16x32_bf16(a0[i], b2, acc[i][j], 0, 0, 0);
                acc[i][j] = __builtin_amdgcn_mfma_f32_16x16x32_bf16(a1[i], b1, acc[i][j], 0, 0, 0);
                acc[i][j] = __builtin_amdgcn_mfma_f32_16x16x32_bf16(a1[i], b0, acc[i][j], 0, 0, 0);
                acc[i][j] = __builtin_amdgcn_mfma_f32_16x16x32_bf16(a0[i], b1, acc[i][j], 0, 0, 0);
                acc[i][j] = __builtin_amdgcn_mfma_f32_16x16x32_bf16(a0[i], b0, acc[i][j], 0, 0, 0);
            }
        }
        __syncthreads();
    }

    if (mode == 0) {
#pragma unroll
        for (int i = 0; i < 4; ++i)
#pragma unroll
            for (int j = 0; j < 4; ++j)
#pragma unroll
                for (int r = 0; r < 4; ++r) {
                    int m = bm + wm + i * 16 + qq * 4 + r;   // C/D: row = quad*4+reg
                    int n = bn + wn + j * 16 + lr;           //      col = lane&15
                    float v = acc[i][j][r] + (n < nreal ? bias[n] : 0.f);
                    v = fmaxf(v, 0.f);
                    store_split3(C0, C1, C2, (size_t)m * NP + n, v);
                }
    } else {
        int pid = ((bn >> 7) << 1) | (wn >> 6);  // 0..15
#pragma unroll
        for (int i = 0; i < 4; ++i)
#pragma unroll
            for (int r = 0; r < 4; ++r) {
                float p = 0.f;
#pragma unroll
                for (int j = 0; j < 4; ++j) {
                    int n = bn + wn + j * 16 + lr;
                    float v = acc[i][j][r] + (n < nreal ? bias[n] : 0.f);
                    v = fmaxf(v, 0.f);
                    p += v * (n < nreal ? w3[n] : 0.f);
                }
                p += __shfl_xor(p, 1);
                p += __shfl_xor(p, 2);
                p += __shfl_xor(p, 4);
                p += __shfl_xor(p, 8);
                if (lr == 0) {
                    int m = bm + wm + i * 16 + qq * 4 + r;
                    partials[(size_t)m * 16 + pid] = p;
                }
            }
    }
}

// ---------------- deterministic score finalize ----------------
__global__ void score_final(const float* __restrict__ partials, const float* __restrict__ b3,
                            const float* __restrict__ width_s, const int* __restrict__ starts,
                            const int* __restrict__ ends, float* __restrict__ out) {
    int c = blockIdx.x * 256 + threadIdx.x;
    if (c >= NUM_CAND) return;
    float s = b3[0] + width_s[ends[c] - starts[c]];
#pragma unroll
    for (int p = 0; p < 16; ++p) s += partials[(size_t)c * 16 + p];
    out[c] = s;
}

// ---------------- sort + speculative-chunked greedy crossing-NMS + final sort ----------------
// NMS latency fixes vs r2 version: (1) packed[] reads are non-volatile and batched into a
// register array -> one waitcnt per chunk instead of 30 serialized 120-cyc round-trips;
// (2) accept broadcast via readlane (wave-uniform f from ballot) instead of 3 ds_bpermute
// shuffles; ord fetched by lane 0 from LDS off the critical path.
__global__ __launch_bounds__(1024) void select_kernel(const float* scores,
                                                      const int* __restrict__ starts,
                                                      const int* __restrict__ ends,
                                                      float* out, int* top_idx_ws) {
    __shared__ unsigned long long keys[NUM_CAND];  // 64 KB union
    char* smem = (char*)keys;
    int t = threadIdx.x;

    for (int i = t; i < NUM_CAND; i += 1024) {
        unsigned int b = __float_as_uint(scores[i]);
        unsigned int u = b ^ ((b & 0x80000000u) ? 0xFFFFFFFFu : 0x80000000u);
        unsigned int hi = ~u;
        keys[i] = ((unsigned long long)hi << 32) | (unsigned int)i;
    }
    __syncthreads();

    for (int size = 2; size <= NUM_CAND; size <<= 1) {
        for (int stride = size >> 1; stride > 0; stride >>= 1) {
            for (int i = t; i < NUM_CAND; i += 1024) {
                int ixj = i ^ stride;
                if (ixj > i) {
                    bool up = ((i & size) == 0);
                    unsigned long long a = keys[i], b = keys[ixj];
                    if ((a > b) == up) { keys[i] = b; keys[ixj] = a; }
                }
            }
            __syncthreads();
        }
    }

    int myidx[8];
#pragma unroll
    for (int q = 0; q < 8; ++q) myidx[q] = (int)(keys[t + q * 1024] & 0xFFFFFFFFull);
    __syncthreads();

    unsigned short* ord_arr = (unsigned short*)smem;
    unsigned int* se_arr = (unsigned int*)(smem + 16384);
    unsigned int* packed = (unsigned int*)(smem + 49152);
    unsigned short* sel = (unsigned short*)(smem + 57344);
    int* count_sh = (int*)(smem + 59392);

#pragma unroll
    for (int q = 0; q < 8; ++q) {
        int i = t + q * 1024;
        int idx = myidx[q];
        int s = starts[idx], e = ends[idx];
        ord_arr[i] = (unsigned short)idx;
        se_arr[i] = ((unsigned int)s << 16) | (unsigned int)e;
    }
    for (int i = t; i < NUM_WORDS; i += 1024) {
        packed[i] = (0u << 16) | (unsigned int)NUM_WORDS;  // max_end=-1, min_start=2048
    }
    if (t == 0) *count_sh = 0;
    __syncthreads();

    if (t < 64) {
        int count = 0;
        for (int i = 0; i < NUM_CAND && count < TOP_NUM; i += 64) {
            int c = i + t;  // NUM_CAND % 64 == 0, always valid
            unsigned int sev = se_arr[c];
            int s = (int)(sev >> 16), e = (int)(sev & 0xFFFFu);
            // batched state reads: indices clamped into [s,e] (always in-bounds)
            unsigned int pv[MSW];
#pragma unroll
            for (int w = 0; w < MSW; ++w) {
                int j = s + w;
                pv[w] = packed[(j <= e) ? j : e];
            }
            int me = (int)(pv[0] >> 16) - 1;
            bool crossed = (s < e) && ((int)(pv[0] & 0xFFFFu) < s);
#pragma unroll
            for (int w = 1; w < MSW; ++w) {
                int j = s + w;
                bool in = (j <= e);
                int mej = (int)(pv[w] >> 16) - 1;
                int msj = (int)(pv[w] & 0xFFFFu);
                crossed = crossed || (in && ((mej > e) || ((j < e) && (msj < s))));
            }
            bool spec = !crossed && (me != e);
            unsigned long long window = ~0ull;
            while (true) {
                unsigned long long b = __ballot(spec) & window;
                if (b == 0ull) break;
                int f = __ffsll((unsigned long long)b) - 1;
                unsigned int sef = __builtin_amdgcn_readlane(sev, (unsigned int)f);
                int sf = (int)(sef >> 16), ef = (int)(sef & 0xFFFFu);
                if (t == 0) {
                    sel[count] = ord_arr[i + f];
                    unsigned int p = packed[sf];
                    unsigned int new_me = max(p >> 16, (unsigned int)(ef + 1));
                    packed[sf] = (new_me << 16) | (p & 0xFFFFu);
                    unsigned int q2 = packed[ef];
                    unsigned int new_ms = min(q2 & 0xFFFFu, (unsigned int)sf);
                    packed[ef] = (q2 & 0xFFFF0000u) | new_ms;
                }
                count++;
                if (count >= TOP_NUM) break;
                window &= (f >= 63) ? 0ull : (~0ull << (f + 1));
                if (t > f) {
                    if (s == sf) me = max(me, ef);
                    crossed = crossed || ((s < sf) && (sf <= e) && (ef > e))
                                      || ((sf < s) && (s <= ef) && (ef < e));
                    spec = !crossed && (me != e);
                }
            }
        }
        if (t == 0) *count_sh = count;
    }
    __syncthreads();
    int count = *count_sh;

    unsigned long long* fkeys = (unsigned long long*)(smem + 49152);  // overlays packed
    {
        unsigned long long k;
        if (t < count) {
            int idx = (int)sel[t];
            unsigned int key32 = (unsigned int)(starts[idx] * NUM_WORDS + ends[idx]);
            k = ((unsigned long long)key32 << 32) | (unsigned int)idx;
        } else {
            k = 0xFFFFFFFFFFFFFFFFull;
        }
        fkeys[t] = k;
    }
    __syncthreads();
    for (int size = 2; size <= 1024; size <<= 1) {
        for (int stride = size >> 1; stride > 0; stride >>= 1) {
            int ixj = t ^ stride;
            if (ixj > t) {
                bool up = ((t & size) == 0);
                unsigned long long a = fkeys[t], b = fkeys[ixj];
                if ((a > b) == up) { fkeys[t] = b; fkeys[ixj] = a; }
            }
            __syncthreads();
        }
    }

    for (int i = t; i < TOP_NUM; i += 1024) {
        int fi = (i < count) ? (int)(fkeys[i] & 0xFFFFFFFFull)
                             : (int)(fkeys[0] & 0xFFFFFFFFull);
        out[OUT_TOPIDX + i] = (float)fi;
        out[OUT_TSTART + i] = (float)starts[fi];
        out[OUT_TEND + i] = (float)ends[fi];
        out[OUT_TSCORE + i] = scores[fi];
        top_idx_ws[i] = fi;
    }
}

// ---------------- gather top_span_emb rows (reconstruct fp32 = a0+a1+a2) ----------------
__global__ void gather_emb(const unsigned short* __restrict__ A0,
                           const unsigned short* __restrict__ A1,
                           const unsigned short* __restrict__ A2,
                           const int* __restrict__ top_idx_ws, float* __restrict__ out) {
    int r = blockIdx.x;
    int idx = top_idx_ws[r];
    const unsigned short* s0 = A0 + (size_t)idx * KP1;
    const unsigned short* s1 = A1 + (size_t)idx * KP1;
    const unsigned short* s2 = A2 + (size_t)idx * KP1;
    float* dst = out + OUT_TEMB + (size_t)r * SPAN_DIM;
    for (int h = threadIdx.x; h < SPAN_DIM; h += blockDim.x)
        dst[h] = bf16_to_f(s0[h]) + bf16_to_f(s1[h]) + bf16_to_f(s2[h]);
}

extern "C" void kernel_launch(void* const* d_in, const int* in_sizes, int n_in,
                              void* d_out, int out_size, void* d_ws, size_t ws_size,
                              hipStream_t stream) {
    const float* mention_doc = (const float*)d_in[0];
    const float* span_width_emb = (const float*)d_in[1];
    const float* head_w = (const float*)d_in[2];
    const float* head_b = (const float*)d_in[3];
    const float* m_w1 = (const float*)d_in[4];
    const float* m_b1 = (const float*)d_in[5];
    const float* m_w2 = (const float*)d_in[6];
    const float* m_b2 = (const float*)d_in[7];
    const float* m_w3 = (const float*)d_in[8];
    const float* m_b3 = (const float*)d_in[9];
    const float* width_prior_emb = (const float*)d_in[10];
    const float* w_w1 = (const float*)d_in[11];
    const float* w_b1 = (const float*)d_in[12];
    const float* w_w2 = (const float*)d_in[13];
    const float* w_b2 = (const float*)d_in[14];
    const float* w_w3 = (const float*)d_in[15];
    const float* w_b3 = (const float*)d_in[16];
    const int* cand_starts = (const int*)d_in[17];
    const int* cand_ends = (const int*)d_in[18];

    char* w = (char*)d_ws;
    const size_t szA = (size_t)NUM_CAND * KP1 * 2;   // 38.27 MB each
    const size_t szH = (size_t)NUM_CAND * NP * 2;    // 16.78 MB each
    const size_t szW1 = (size_t)NP * KP1 * 2;        // 4.78 MB each
    const size_t szW2 = (size_t)NP * KP2 * 2;        // 2.10 MB each
    unsigned short* A0 = (unsigned short*)w;
    unsigned short* A1 = (unsigned short*)(w + szA);
    unsigned short* A2 = (unsigned short*)(w + 2 * szA);
    char* p = w + 3 * szA;
    unsigned short* h0 = (unsigned short*)p;
    unsigned short* h1 = (unsigned short*)(p + szH);
    unsigned short* h2 = (unsigned short*)(p + 2 * szH);
    p += 3 * szH;
    unsigned short* w1t0 = (unsigned short*)p;
    unsigned short* w1t1 = (unsigned short*)(p + szW1);
    unsigned short* w1t2 = (unsigned short*)(p + 2 * szW1);
    p += 3 * szW1;
    unsigned short* w2t0 = (unsigned short*)p;
    unsigned short* w2t1 = (unsigned short*)(p + szW2);
    unsigned short* w2t2 = (unsigned short*)(p + 2 * szW2);
    p += 3 * szW2;
    float* partials = (float*)p;                    // 8192*16 floats
    p += (size_t)NUM_CAND * 16 * 4;
    float* head_s = (float*)p;                      // 2048 floats
    float* width_s = (float*)(p + 8192);            // 32 floats
    int* top_idx_ws = (int*)(p + 8192 + 128);       // 1024 ints

    size_t need = (size_t)(p - w) + 8192 + 128 + 4096;
    if (ws_size < need) {
        fprintf(stderr, "kernel_launch: ws too small (%zu < %zu)\n", ws_size, need);
    }

    float* out = (float*)d_out;

    head_kernel<<<NUM_WORDS / 4, 256, 0, stream>>>(mention_doc, head_w, head_b, head_s);
    width_kernel<<<MSW, 256, 0, stream>>>(width_prior_emb, w_w1, w_b1, w_w2, w_b2, w_w3, w_b3,
                                          width_s);
    convert_wt<<<dim3((KP1 + 255) / 256, NP), 256, 0, stream>>>(m_w1, SPAN_DIM, FFNN_DIM, KP1,
                                                                w1t0, w1t1, w1t2);
    convert_wt<<<dim3((KP2 + 255) / 256, NP), 256, 0, stream>>>(m_w2, FFNN_DIM, FFNN_DIM, KP2,
                                                                w2t0, w2t1, w2t2);
    span_emb_kernel<<<NUM_CAND, 256, 0, stream>>>(mention_doc, span_width_emb, head_s,
                                                  cand_starts, cand_ends, A0, A1, A2);
    gemm6<<<512, 256, 0, stream>>>(A0, A1, A2, w1t0, w1t1, w1t2, m_b1, FFNN_DIM, KP1, 0,
                                   h0, h1, h2, nullptr, nullptr);
    gemm6<<<512, 256, 0, stream>>>(h0, h1, h2, w2t0, w2t1, w2t2, m_b2, FFNN_DIM, KP2, 1,
                                   nullptr, nullptr, nullptr, m_w3, partials);
    score_final<<<NUM_CAND / 256, 256, 0, stream>>>(partials, m_b3, width_s, cand_starts,
                                                    cand_ends, out);
    select_kernel<<<1, 1024, 0, stream>>>(out, cand_starts, cand_ends, out, top_idx_ws);
    gather_emb<<<TOP_NUM, 256, 0, stream>>>(A0, A1, A2, top_idx_ws, out);
}

// Round 6
// 1016.720 us; speedup vs baseline: 2.9566x; 1.0814x over previous
//
#include <hip/hip_runtime.h>
#include <cstdio>
#include <cmath>

#define NUM_WORDS 2048
#define NUM_CAND 8192
#define HIDDEN 768
#define FEAT 20
#define FFNN_DIM 1000
#define SPAN_DIM 2324
#define TOP_NUM 819
#define MSW 30
#define KP1 2336   // SPAN_DIM padded to x32
#define KP2 1024   // FFNN padded to x32
#define NP 1024    // padded N

// d_out layout (floats): [scores 8192][top_idx 819][top_starts 819][top_ends 819]
//                        [top_span_emb 819*2324][top_scores 819]
#define OUT_TOPIDX   (NUM_CAND)
#define OUT_TSTART   (NUM_CAND + TOP_NUM)
#define OUT_TEND     (NUM_CAND + 2*TOP_NUM)
#define OUT_TEMB     (NUM_CAND + 3*TOP_NUM)
#define OUT_TSCORE   (NUM_CAND + 3*TOP_NUM + TOP_NUM*SPAN_DIM)

typedef short short8 __attribute__((ext_vector_type(8)));
typedef float f32x4 __attribute__((ext_vector_type(4)));

__device__ __forceinline__ unsigned short bf16_rne(float x) {
    unsigned int u = __float_as_uint(x);
    unsigned int r = u + 0x7FFFu + ((u >> 16) & 1u);
    return (unsigned short)(r >> 16);
}
__device__ __forceinline__ float bf16_to_f(unsigned short h) {
    return __uint_as_float(((unsigned int)h) << 16);
}
// 3-way split: v = s0 + s1 + s2 + r, |r| <= 2^-27 |v|
__device__ __forceinline__ void store_split3(unsigned short* p0, unsigned short* p1,
                                             unsigned short* p2, size_t off, float v) {
    unsigned short h0 = bf16_rne(v);
    float r1 = v - bf16_to_f(h0);
    unsigned short h1 = bf16_rne(r1);
    float r2 = r1 - bf16_to_f(h1);
    p0[off] = h0;
    p1[off] = h1;
    p2[off] = bf16_rne(r2);
}

// ---------------- head scores: doc @ head_w + head_b  -> [2048] ----------------
__global__ void head_kernel(const float* __restrict__ doc, const float* __restrict__ hw,
                            const float* __restrict__ hb, float* __restrict__ out) {
    int wave = threadIdx.x >> 6, lane = threadIdx.x & 63;
    int row = blockIdx.x * 4 + wave;
    if (row >= NUM_WORDS) return;
    float acc = 0.f;
    for (int h = lane; h < HIDDEN; h += 64) acc += doc[row * HIDDEN + h] * hw[h];
    for (int off = 32; off > 0; off >>= 1) acc += __shfl_down(acc, off);
    if (lane == 0) out[row] = acc + hb[0];
}

// ---------------- width prior ffnn: [30,20] -> [30] ----------------
__global__ void width_kernel(const float* __restrict__ x, const float* __restrict__ w1,
                             const float* __restrict__ b1, const float* __restrict__ w2,
                             const float* __restrict__ b2, const float* __restrict__ w3,
                             const float* __restrict__ b3, float* __restrict__ out) {
    __shared__ float xs[FEAT];
    __shared__ float h1s[FFNN_DIM];
    __shared__ float red[256];
    int r = blockIdx.x, t = threadIdx.x;
    if (t < FEAT) xs[t] = x[r * FEAT + t];
    __syncthreads();
    for (int j = t; j < FFNN_DIM; j += 256) {
        float acc = b1[j];
        for (int k = 0; k < FEAT; ++k) acc += xs[k] * w1[k * FFNN_DIM + j];
        h1s[j] = fmaxf(acc, 0.f);
    }
    __syncthreads();
    float partial = 0.f;
    for (int j = t; j < FFNN_DIM; j += 256) {
        float acc = b2[j];
        for (int k = 0; k < FFNN_DIM; ++k) acc += h1s[k] * w2[k * FFNN_DIM + j];
        partial += fmaxf(acc, 0.f) * w3[j];
    }
    red[t] = partial;
    __syncthreads();
    for (int s = 128; s > 0; s >>= 1) { if (t < s) red[t] += red[t + s]; __syncthreads(); }
    if (t == 0) out[r] = red[0] + b3[0];
}

// ---------------- weight convert+transpose: w[K][N] -> 3-split [NP][Kp] (zero-padded) ------
__global__ void convert_wt(const float* __restrict__ w, int K, int N, int Kp,
                           unsigned short* __restrict__ q0, unsigned short* __restrict__ q1,
                           unsigned short* __restrict__ q2) {
    int n = blockIdx.y;
    int k = blockIdx.x * blockDim.x + threadIdx.x;
    if (k >= Kp) return;
    float v = (k < K && n < N) ? w[(size_t)k * N + n] : 0.f;
    store_split3(q0, q1, q2, (size_t)n * Kp + k, v);
}

// ---------------- span embedding -> A 3-split bf16 [8192][2336] ----------------
__global__ void span_emb_kernel(const float* __restrict__ doc, const float* __restrict__ swe,
                                const float* __restrict__ head_s, const int* __restrict__ starts,
                                const int* __restrict__ ends,
                                unsigned short* __restrict__ A0, unsigned short* __restrict__ A1,
                                unsigned short* __restrict__ A2) {
    int c = blockIdx.x;
    int s = starts[c], e = ends[c];
    int wid = e - s;  // 0..29
    __shared__ float attn[MSW];
    int t = threadIdx.x;
    if (t < 64) {
        int w = t;
        float hsv = -INFINITY;
        if (w < MSW && w <= wid) hsv = head_s[s + w];
        float m = hsv;
        for (int off = 32; off > 0; off >>= 1) m = fmaxf(m, __shfl_down(m, off));
        m = __shfl(m, 0);
        float ex = (w < MSW && w <= wid) ? expf(hsv - m) : 0.f;
        float ssum = ex;
        for (int off = 32; off > 0; off >>= 1) ssum += __shfl_down(ssum, off);
        ssum = __shfl(ssum, 0);
        if (w < MSW) attn[w] = ex / ssum;
    }
    __syncthreads();
    size_t base = (size_t)c * KP1;
    for (int h = t; h < HIDDEN; h += blockDim.x) {
        float v0 = doc[s * HIDDEN + h];
        float v1 = doc[e * HIDDEN + h];
        float accv = 0.f;
        for (int w = 0; w <= wid; ++w) accv += attn[w] * doc[(s + w) * HIDDEN + h];
        store_split3(A0, A1, A2, base + h, v0);
        store_split3(A0, A1, A2, base + HIDDEN + h, v1);
        store_split3(A0, A1, A2, base + 2 * HIDDEN + FEAT + h, accv);
    }
    if (t < FEAT) store_split3(A0, A1, A2, base + 2 * HIDDEN + t, swe[wid * FEAT + t]);
    if (t < KP1 - SPAN_DIM) {
        A0[base + SPAN_DIM + t] = 0; A1[base + SPAN_DIM + t] = 0; A2[base + SPAN_DIM + t] = 0;
    }
}

// ---------------- 3-split 6-product MFMA GEMM ----------------
__global__ __launch_bounds__(256, 2) void gemm6(
    const unsigned short* __restrict__ A0, const unsigned short* __restrict__ A1,
    const unsigned short* __restrict__ A2,
    const unsigned short* __restrict__ B0, const unsigned short* __restrict__ B1,
    const unsigned short* __restrict__ B2,
    const float* __restrict__ bias, int nreal, int Kp, int mode,
    unsigned short* __restrict__ C0, unsigned short* __restrict__ C1,
    unsigned short* __restrict__ C2,
    const float* __restrict__ w3, float* __restrict__ partials) {
    __shared__ unsigned short As0[128 * 40], As1[128 * 40], As2[128 * 40];
    __shared__ unsigned short Bs0[128 * 40], Bs1[128 * 40], Bs2[128 * 40];
    int t = threadIdx.x;
    int bid = blockIdx.x;
    // 8x8 supertile swizzle: 8 consecutive m-blocks share B in L2/L3
    int sm = bid >> 6, idx = bid & 63;
    int bm = ((sm << 3) + (idx & 7)) << 7;
    int bn = (idx >> 3) << 7;
    int lane = t & 63, wv = t >> 6;
    int wm = (wv >> 1) * 64, wn = (wv & 1) * 64;
    int lr = lane & 15, qq = lane >> 4;

    f32x4 acc[4][4] = {};

    for (int k0 = 0; k0 < Kp; k0 += 32) {
#pragma unroll
        for (int qi = 0; qi < 2; ++qi) {
            int u = qi * 256 + t;
            int m = u >> 2, blk = u & 3;
            size_t ga = (size_t)(bm + m) * Kp + k0 + blk * 8;
            size_t gb = (size_t)(bn + m) * Kp + k0 + blk * 8;
            uint4 va0 = *(const uint4*)(A0 + ga);
            uint4 va1 = *(const uint4*)(A1 + ga);
            uint4 va2 = *(const uint4*)(A2 + ga);
            uint4 vb0 = *(const uint4*)(B0 + gb);
            uint4 vb1 = *(const uint4*)(B1 + gb);
            uint4 vb2 = *(const uint4*)(B2 + gb);
            int la = m * 40 + blk * 8;
            *(uint4*)&As0[la] = va0;
            *(uint4*)&As1[la] = va1;
            *(uint4*)&As2[la] = va2;
            *(uint4*)&Bs0[la] = vb0;
            *(uint4*)&Bs1[la] = vb1;
            *(uint4*)&Bs2[la] = vb2;
        }
        __syncthreads();
        short8 a0[4], a1[4], a2[4];
#pragma unroll
        for (int i = 0; i < 4; ++i) {
            int ra = (wm + i * 16 + lr) * 40 + qq * 8;
            a0[i] = *(const short8*)&As0[ra];
            a1[i] = *(const short8*)&As1[ra];
            a2[i] = *(const short8*)&As2[ra];
        }
#pragma unroll
        for (int j = 0; j < 4; ++j) {
            int rb = (wn + j * 16 + lr) * 40 + qq * 8;
            short8 b0 = *(const short8*)&Bs0[rb];
            short8 b1 = *(const short8*)&Bs1[rb];
            short8 b2 = *(const short8*)&Bs2[rb];
#pragma unroll
            for (int i = 0; i < 4; ++i) {
                acc[i][j] = __builtin_amdgcn_mfma_f32_16x16x32_bf16(a2[i], b0, acc[i][j], 0, 0, 0);
                acc[i][j] = __builtin_amdgcn_mfma_f32_16x16x32_bf16(a0[i], b2, acc[i][j], 0, 0, 0);
                acc[i][j] = __builtin_amdgcn_mfma_f32_16x16x32_bf16(a1[i], b1, acc[i][j], 0, 0, 0);
                acc[i][j] = __builtin_amdgcn_mfma_f32_16x16x32_bf16(a1[i], b0, acc[i][j], 0, 0, 0);
                acc[i][j] = __builtin_amdgcn_mfma_f32_16x16x32_bf16(a0[i], b1, acc[i][j], 0, 0, 0);
                acc[i][j] = __builtin_amdgcn_mfma_f32_16x16x32_bf16(a0[i], b0, acc[i][j], 0, 0, 0);
            }
        }
        __syncthreads();
    }

    if (mode == 0) {
#pragma unroll
        for (int i = 0; i < 4; ++i)
#pragma unroll
            for (int j = 0; j < 4; ++j)
#pragma unroll
                for (int r = 0; r < 4; ++r) {
                    int m = bm + wm + i * 16 + qq * 4 + r;   // C/D: row = quad*4+reg
                    int n = bn + wn + j * 16 + lr;           //      col = lane&15
                    float v = acc[i][j][r] + (n < nreal ? bias[n] : 0.f);
                    v = fmaxf(v, 0.f);
                    store_split3(C0, C1, C2, (size_t)m * NP + n, v);
                }
    } else {
        int pid = ((bn >> 7) << 1) | (wn >> 6);  // 0..15
#pragma unroll
        for (int i = 0; i < 4; ++i)
#pragma unroll
            for (int r = 0; r < 4; ++r) {
                float p = 0.f;
#pragma unroll
                for (int j = 0; j < 4; ++j) {
                    int n = bn + wn + j * 16 + lr;
                    float v = acc[i][j][r] + (n < nreal ? bias[n] : 0.f);
                    v = fmaxf(v, 0.f);
                    p += v * (n < nreal ? w3[n] : 0.f);
                }
                p += __shfl_xor(p, 1);
                p += __shfl_xor(p, 2);
                p += __shfl_xor(p, 4);
                p += __shfl_xor(p, 8);
                if (lr == 0) {
                    int m = bm + wm + i * 16 + qq * 4 + r;
                    partials[(size_t)m * 16 + pid] = p;
                }
            }
    }
}

// ---------------- deterministic score finalize ----------------
__global__ void score_final(const float* __restrict__ partials, const float* __restrict__ b3,
                            const float* __restrict__ width_s, const int* __restrict__ starts,
                            const int* __restrict__ ends, float* __restrict__ out) {
    int c = blockIdx.x * 256 + threadIdx.x;
    if (c >= NUM_CAND) return;
    float s = b3[0] + width_s[ends[c] - starts[c]];
#pragma unroll
    for (int p = 0; p < 16; ++p) s += partials[(size_t)c * 16 + p];
    out[c] = s;
}

// ---------------- exact counting rank-sort: 256 blocks, replaces single-CU bitonic ---------
// key64 = (~monotone(score) << 32) | idx  -> ascending key64 == descending score, idx tiebreak.
// rank(i) = #{j : key64[j] < key64[i]} (exact, all keys distinct). 8 lanes per candidate,
// each counts 1024 LDS-broadcast keys; 3x shfl_xor combine; scatter ord/se at rank.
__global__ __launch_bounds__(256) void rank_kernel(const float* __restrict__ scores,
                                                   const int* __restrict__ starts,
                                                   const int* __restrict__ ends,
                                                   unsigned short* __restrict__ ord_g,
                                                   unsigned int* __restrict__ se_g) {
    __shared__ unsigned long long kk[NUM_CAND];  // 64 KB
    int t = threadIdx.x;
    for (int i = t; i < NUM_CAND; i += 256) {
        unsigned int b = __float_as_uint(scores[i]);
        unsigned int u = b ^ ((b & 0x80000000u) ? 0xFFFFFFFFu : 0x80000000u);
        unsigned int hi = ~u;
        kk[i] = ((unsigned long long)hi << 32) | (unsigned int)i;
    }
    __syncthreads();
    int c = blockIdx.x * 32 + (t >> 3);      // candidate handled by this 8-lane group
    int seg = (t & 7) * 1024;
    unsigned long long mykey = kk[c];
    int cnt = 0;
    for (int i = seg; i < seg + 1024; ++i) cnt += (kk[i] < mykey) ? 1 : 0;
    cnt += __shfl_xor(cnt, 1);
    cnt += __shfl_xor(cnt, 2);
    cnt += __shfl_xor(cnt, 4);
    if ((t & 7) == 0) {
        int idx = (int)(mykey & 0xFFFFFFFFull);
        int rank = cnt;
        ord_g[rank] = (unsigned short)idx;
        se_g[rank] = ((unsigned int)starts[idx] << 16) | (unsigned int)ends[idx];
    }
}

// ---------------- speculative-chunked greedy crossing-NMS + final small sort ----------------
// Consumes pre-sorted (ord_g, se_g) from rank_kernel. NMS logic unchanged (verified r2/r4/r5).
__global__ __launch_bounds__(1024) void select_kernel(const float* scores,
                                                      const int* __restrict__ starts,
                                                      const int* __restrict__ ends,
                                                      const unsigned short* __restrict__ ord_g,
                                                      const unsigned int* __restrict__ se_g,
                                                      float* out, int* top_idx_ws) {
    __shared__ char smem[60416];
    int t = threadIdx.x;

    unsigned short* ord_arr = (unsigned short*)smem;                 // 16 KB @ 0
    unsigned int* se_arr = (unsigned int*)(smem + 16384);            // 32 KB @ 16K
    unsigned int* packed = (unsigned int*)(smem + 49152);            //  8 KB @ 48K
    unsigned short* sel = (unsigned short*)(smem + 57344);           //  2 KB @ 56K
    int* count_sh = (int*)(smem + 59392);

    for (int i = t; i < NUM_CAND; i += 1024) {
        ord_arr[i] = ord_g[i];
        se_arr[i] = se_g[i];
    }
    for (int i = t; i < NUM_WORDS; i += 1024) {
        packed[i] = (0u << 16) | (unsigned int)NUM_WORDS;  // max_end=-1, min_start=2048
    }
    if (t == 0) *count_sh = 0;
    __syncthreads();

    if (t < 64) {
        int count = 0;
        for (int i = 0; i < NUM_CAND && count < TOP_NUM; i += 64) {
            int c = i + t;  // NUM_CAND % 64 == 0, always valid
            unsigned int sev = se_arr[c];
            int s = (int)(sev >> 16), e = (int)(sev & 0xFFFFu);
            // batched state reads: indices clamped into [s,e] (always in-bounds)
            unsigned int pv[MSW];
#pragma unroll
            for (int w = 0; w < MSW; ++w) {
                int j = s + w;
                pv[w] = packed[(j <= e) ? j : e];
            }
            int me = (int)(pv[0] >> 16) - 1;
            bool crossed = (s < e) && ((int)(pv[0] & 0xFFFFu) < s);
#pragma unroll
            for (int w = 1; w < MSW; ++w) {
                int j = s + w;
                bool in = (j <= e);
                int mej = (int)(pv[w] >> 16) - 1;
                int msj = (int)(pv[w] & 0xFFFFu);
                crossed = crossed || (in && ((mej > e) || ((j < e) && (msj < s))));
            }
            bool spec = !crossed && (me != e);
            unsigned long long window = ~0ull;
            while (true) {
                unsigned long long b = __ballot(spec) & window;
                if (b == 0ull) break;
                int f = __ffsll((unsigned long long)b) - 1;
                unsigned int sef = __builtin_amdgcn_readlane(sev, (unsigned int)f);
                int sf = (int)(sef >> 16), ef = (int)(sef & 0xFFFFu);
                if (t == 0) {
                    sel[count] = ord_arr[i + f];
                    unsigned int p = packed[sf];
                    unsigned int new_me = max(p >> 16, (unsigned int)(ef + 1));
                    packed[sf] = (new_me << 16) | (p & 0xFFFFu);
                    unsigned int q2 = packed[ef];
                    unsigned int new_ms = min(q2 & 0xFFFFu, (unsigned int)sf);
                    packed[ef] = (q2 & 0xFFFF0000u) | new_ms;
                }
                count++;
                if (count >= TOP_NUM) break;
                window &= (f >= 63) ? 0ull : (~0ull << (f + 1));
                if (t > f) {
                    if (s == sf) me = max(me, ef);
                    crossed = crossed || ((s < sf) && (sf <= e) && (ef > e))
                                      || ((sf < s) && (s <= ef) && (ef < e));
                    spec = !crossed && (me != e);
                }
            }
        }
        if (t == 0) *count_sh = count;
    }
    __syncthreads();
    int count = *count_sh;

    // final sort of selected spans by (start*2048 + end), pad to 1024 with MAX keys
    unsigned long long* fkeys = (unsigned long long*)(smem + 49152);  // overlays packed
    {
        unsigned long long k;
        if (t < count) {
            int idx = (int)sel[t];
            unsigned int key32 = (unsigned int)(starts[idx] * NUM_WORDS + ends[idx]);
            k = ((unsigned long long)key32 << 32) | (unsigned int)idx;
        } else {
            k = 0xFFFFFFFFFFFFFFFFull;
        }
        fkeys[t] = k;
    }
    __syncthreads();
    for (int size = 2; size <= 1024; size <<= 1) {
        for (int stride = size >> 1; stride > 0; stride >>= 1) {
            int ixj = t ^ stride;
            if (ixj > t) {
                bool up = ((t & size) == 0);
                unsigned long long a = fkeys[t], b = fkeys[ixj];
                if ((a > b) == up) { fkeys[t] = b; fkeys[ixj] = a; }
            }
            __syncthreads();
        }
    }

    for (int i = t; i < TOP_NUM; i += 1024) {
        int fi = (i < count) ? (int)(fkeys[i] & 0xFFFFFFFFull)
                             : (int)(fkeys[0] & 0xFFFFFFFFull);
        out[OUT_TOPIDX + i] = (float)fi;
        out[OUT_TSTART + i] = (float)starts[fi];
        out[OUT_TEND + i] = (float)ends[fi];
        out[OUT_TSCORE + i] = scores[fi];
        top_idx_ws[i] = fi;
    }
}

// ---------------- gather top_span_emb rows (reconstruct fp32 = a0+a1+a2) ----------------
__global__ void gather_emb(const unsigned short* __restrict__ A0,
                           const unsigned short* __restrict__ A1,
                           const unsigned short* __restrict__ A2,
                           const int* __restrict__ top_idx_ws, float* __restrict__ out) {
    int r = blockIdx.x;
    int idx = top_idx_ws[r];
    const unsigned short* s0 = A0 + (size_t)idx * KP1;
    const unsigned short* s1 = A1 + (size_t)idx * KP1;
    const unsigned short* s2 = A2 + (size_t)idx * KP1;
    float* dst = out + OUT_TEMB + (size_t)r * SPAN_DIM;
    for (int h = threadIdx.x; h < SPAN_DIM; h += blockDim.x)
        dst[h] = bf16_to_f(s0[h]) + bf16_to_f(s1[h]) + bf16_to_f(s2[h]);
}

extern "C" void kernel_launch(void* const* d_in, const int* in_sizes, int n_in,
                              void* d_out, int out_size, void* d_ws, size_t ws_size,
                              hipStream_t stream) {
    const float* mention_doc = (const float*)d_in[0];
    const float* span_width_emb = (const float*)d_in[1];
    const float* head_w = (const float*)d_in[2];
    const float* head_b = (const float*)d_in[3];
    const float* m_w1 = (const float*)d_in[4];
    const float* m_b1 = (const float*)d_in[5];
    const float* m_w2 = (const float*)d_in[6];
    const float* m_b2 = (const float*)d_in[7];
    const float* m_w3 = (const float*)d_in[8];
    const float* m_b3 = (const float*)d_in[9];
    const float* width_prior_emb = (const float*)d_in[10];
    const float* w_w1 = (const float*)d_in[11];
    const float* w_b1 = (const float*)d_in[12];
    const float* w_w2 = (const float*)d_in[13];
    const float* w_b2 = (const float*)d_in[14];
    const float* w_w3 = (const float*)d_in[15];
    const float* w_b3 = (const float*)d_in[16];
    const int* cand_starts = (const int*)d_in[17];
    const int* cand_ends = (const int*)d_in[18];

    char* w = (char*)d_ws;
    const size_t szA = (size_t)NUM_CAND * KP1 * 2;   // 38.27 MB each
    const size_t szH = (size_t)NUM_CAND * NP * 2;    // 16.78 MB each
    const size_t szW1 = (size_t)NP * KP1 * 2;        // 4.78 MB each
    const size_t szW2 = (size_t)NP * KP2 * 2;        // 2.10 MB each
    unsigned short* A0 = (unsigned short*)w;
    unsigned short* A1 = (unsigned short*)(w + szA);
    unsigned short* A2 = (unsigned short*)(w + 2 * szA);
    char* p = w + 3 * szA;
    unsigned short* h0 = (unsigned short*)p;
    unsigned short* h1 = (unsigned short*)(p + szH);
    unsigned short* h2 = (unsigned short*)(p + 2 * szH);
    p += 3 * szH;
    unsigned short* w1t0 = (unsigned short*)p;
    unsigned short* w1t1 = (unsigned short*)(p + szW1);
    unsigned short* w1t2 = (unsigned short*)(p + 2 * szW1);
    p += 3 * szW1;
    unsigned short* w2t0 = (unsigned short*)p;
    unsigned short* w2t1 = (unsigned short*)(p + szW2);
    unsigned short* w2t2 = (unsigned short*)(p + 2 * szW2);
    p += 3 * szW2;
    float* partials = (float*)p;                    // 8192*16 floats
    p += (size_t)NUM_CAND * 16 * 4;
    unsigned short* ord_g = (unsigned short*)p;     // 8192 u16
    p += (size_t)NUM_CAND * 2;
    unsigned int* se_g = (unsigned int*)p;          // 8192 u32
    p += (size_t)NUM_CAND * 4;
    float* head_s = (float*)p;                      // 2048 floats
    float* width_s = (float*)(p + 8192);            // 32 floats
    int* top_idx_ws = (int*)(p + 8192 + 128);       // 1024 ints

    size_t need = (size_t)(p - w) + 8192 + 128 + 4096;
    if (ws_size < need) {
        fprintf(stderr, "kernel_launch: ws too small (%zu < %zu)\n", ws_size, need);
    }

    float* out = (float*)d_out;

    head_kernel<<<NUM_WORDS / 4, 256, 0, stream>>>(mention_doc, head_w, head_b, head_s);
    width_kernel<<<MSW, 256, 0, stream>>>(width_prior_emb, w_w1, w_b1, w_w2, w_b2, w_w3, w_b3,
                                          width_s);
    convert_wt<<<dim3((KP1 + 255) / 256, NP), 256, 0, stream>>>(m_w1, SPAN_DIM, FFNN_DIM, KP1,
                                                                w1t0, w1t1, w1t2);
    convert_wt<<<dim3((KP2 + 255) / 256, NP), 256, 0, stream>>>(m_w2, FFNN_DIM, FFNN_DIM, KP2,
                                                                w2t0, w2t1, w2t2);
    span_emb_kernel<<<NUM_CAND, 256, 0, stream>>>(mention_doc, span_width_emb, head_s,
                                                  cand_starts, cand_ends, A0, A1, A2);
    gemm6<<<512, 256, 0, stream>>>(A0, A1, A2, w1t0, w1t1, w1t2, m_b1, FFNN_DIM, KP1, 0,
                                   h0, h1, h2, nullptr, nullptr);
    gemm6<<<512, 256, 0, stream>>>(h0, h1, h2, w2t0, w2t1, w2t2, m_b2, FFNN_DIM, KP2, 1,
                                   nullptr, nullptr, nullptr, m_w3, partials);
    score_final<<<NUM_CAND / 256, 256, 0, stream>>>(partials, m_b3, width_s, cand_starts,
                                                    cand_ends, out);
    rank_kernel<<<NUM_CAND / 32, 256, 0, stream>>>(out, cand_starts, cand_ends, ord_g, se_g);
    select_kernel<<<1, 1024, 0, stream>>>(out, cand_starts, cand_ends, ord_g, se_g, out,
                                          top_idx_ws);
    gather_emb<<<TOP_NUM, 256, 0, stream>>>(A0, A1, A2, top_idx_ws, out);
}

// Round 7
// 1009.724 us; speedup vs baseline: 2.9771x; 1.0069x over previous
//
#include <hip/hip_runtime.h>
#include <cstdio>
#include <cmath>

#define NUM_WORDS 2048
#define NUM_CAND 8192
#define HIDDEN 768
#define FEAT 20
#define FFNN_DIM 1000
#define SPAN_DIM 2324
#define TOP_NUM 819
#define MSW 30
#define KP1 2336   // SPAN_DIM padded to x32
#define KP2 1024   // FFNN padded to x32
#define NP 1024    // padded N

// d_out layout (floats): [scores 8192][top_idx 819][top_starts 819][top_ends 819]
//                        [top_span_emb 819*2324][top_scores 819]
#define OUT_TOPIDX   (NUM_CAND)
#define OUT_TSTART   (NUM_CAND + TOP_NUM)
#define OUT_TEND     (NUM_CAND + 2*TOP_NUM)
#define OUT_TEMB     (NUM_CAND + 3*TOP_NUM)
#define OUT_TSCORE   (NUM_CAND + 3*TOP_NUM + TOP_NUM*SPAN_DIM)

typedef short short8 __attribute__((ext_vector_type(8)));
typedef float f32x4 __attribute__((ext_vector_type(4)));

__device__ __forceinline__ unsigned short bf16_rne(float x) {
    unsigned int u = __float_as_uint(x);
    unsigned int r = u + 0x7FFFu + ((u >> 16) & 1u);
    return (unsigned short)(r >> 16);
}
__device__ __forceinline__ float bf16_to_f(unsigned short h) {
    return __uint_as_float(((unsigned int)h) << 16);
}
// 3-way split: v = s0 + s1 + s2 + r, |r| <= 2^-27 |v|
__device__ __forceinline__ void store_split3(unsigned short* p0, unsigned short* p1,
                                             unsigned short* p2, size_t off, float v) {
    unsigned short h0 = bf16_rne(v);
    float r1 = v - bf16_to_f(h0);
    unsigned short h1 = bf16_rne(r1);
    float r2 = r1 - bf16_to_f(h1);
    p0[off] = h0;
    p1[off] = h1;
    p2[off] = bf16_rne(r2);
}

// ---------------- head scores: doc @ head_w + head_b  -> [2048] ----------------
__global__ void head_kernel(const float* __restrict__ doc, const float* __restrict__ hw,
                            const float* __restrict__ hb, float* __restrict__ out) {
    int wave = threadIdx.x >> 6, lane = threadIdx.x & 63;
    int row = blockIdx.x * 4 + wave;
    if (row >= NUM_WORDS) return;
    float acc = 0.f;
    for (int h = lane; h < HIDDEN; h += 64) acc += doc[row * HIDDEN + h] * hw[h];
    for (int off = 32; off > 0; off >>= 1) acc += __shfl_down(acc, off);
    if (lane == 0) out[row] = acc + hb[0];
}

// ---------------- width prior ffnn: [30,20] -> [30] ----------------
__global__ void width_kernel(const float* __restrict__ x, const float* __restrict__ w1,
                             const float* __restrict__ b1, const float* __restrict__ w2,
                             const float* __restrict__ b2, const float* __restrict__ w3,
                             const float* __restrict__ b3, float* __restrict__ out) {
    __shared__ float xs[FEAT];
    __shared__ float h1s[FFNN_DIM];
    __shared__ float red[256];
    int r = blockIdx.x, t = threadIdx.x;
    if (t < FEAT) xs[t] = x[r * FEAT + t];
    __syncthreads();
    for (int j = t; j < FFNN_DIM; j += 256) {
        float acc = b1[j];
        for (int k = 0; k < FEAT; ++k) acc += xs[k] * w1[k * FFNN_DIM + j];
        h1s[j] = fmaxf(acc, 0.f);
    }
    __syncthreads();
    float partial = 0.f;
    for (int j = t; j < FFNN_DIM; j += 256) {
        float acc = b2[j];
        for (int k = 0; k < FFNN_DIM; ++k) acc += h1s[k] * w2[k * FFNN_DIM + j];
        partial += fmaxf(acc, 0.f) * w3[j];
    }
    red[t] = partial;
    __syncthreads();
    for (int s = 128; s > 0; s >>= 1) { if (t < s) red[t] += red[t + s]; __syncthreads(); }
    if (t == 0) out[r] = red[0] + b3[0];
}

// ---------------- weight convert+transpose: w[K][N] -> 3-split [NP][Kp] (zero-padded) ------
__global__ void convert_wt(const float* __restrict__ w, int K, int N, int Kp,
                           unsigned short* __restrict__ q0, unsigned short* __restrict__ q1,
                           unsigned short* __restrict__ q2) {
    int n = blockIdx.y;
    int k = blockIdx.x * blockDim.x + threadIdx.x;
    if (k >= Kp) return;
    float v = (k < K && n < N) ? w[(size_t)k * N + n] : 0.f;
    store_split3(q0, q1, q2, (size_t)n * Kp + k, v);
}

// ---------------- span embedding -> A 3-split bf16 [8192][2336] ----------------
__global__ void span_emb_kernel(const float* __restrict__ doc, const float* __restrict__ swe,
                                const float* __restrict__ head_s, const int* __restrict__ starts,
                                const int* __restrict__ ends,
                                unsigned short* __restrict__ A0, unsigned short* __restrict__ A1,
                                unsigned short* __restrict__ A2) {
    int c = blockIdx.x;
    int s = starts[c], e = ends[c];
    int wid = e - s;  // 0..29
    __shared__ float attn[MSW];
    int t = threadIdx.x;
    if (t < 64) {
        int w = t;
        float hsv = -INFINITY;
        if (w < MSW && w <= wid) hsv = head_s[s + w];
        float m = hsv;
        for (int off = 32; off > 0; off >>= 1) m = fmaxf(m, __shfl_down(m, off));
        m = __shfl(m, 0);
        float ex = (w < MSW && w <= wid) ? expf(hsv - m) : 0.f;
        float ssum = ex;
        for (int off = 32; off > 0; off >>= 1) ssum += __shfl_down(ssum, off);
        ssum = __shfl(ssum, 0);
        if (w < MSW) attn[w] = ex / ssum;
    }
    __syncthreads();
    size_t base = (size_t)c * KP1;
    for (int h = t; h < HIDDEN; h += blockDim.x) {
        float v0 = doc[s * HIDDEN + h];
        float v1 = doc[e * HIDDEN + h];
        float accv = 0.f;
        for (int w = 0; w <= wid; ++w) accv += attn[w] * doc[(s + w) * HIDDEN + h];
        store_split3(A0, A1, A2, base + h, v0);
        store_split3(A0, A1, A2, base + HIDDEN + h, v1);
        store_split3(A0, A1, A2, base + 2 * HIDDEN + FEAT + h, accv);
    }
    if (t < FEAT) store_split3(A0, A1, A2, base + 2 * HIDDEN + t, swe[wid * FEAT + t]);
    if (t < KP1 - SPAN_DIM) {
        A0[base + SPAN_DIM + t] = 0; A1[base + SPAN_DIM + t] = 0; A2[base + SPAN_DIM + t] = 0;
    }
}

// ---------------- 3-split 6-product MFMA GEMM ----------------
__global__ __launch_bounds__(256, 2) void gemm6(
    const unsigned short* __restrict__ A0, const unsigned short* __restrict__ A1,
    const unsigned short* __restrict__ A2,
    const unsigned short* __restrict__ B0, const unsigned short* __restrict__ B1,
    const unsigned short* __restrict__ B2,
    const float* __restrict__ bias, int nreal, int Kp, int mode,
    unsigned short* __restrict__ C0, unsigned short* __restrict__ C1,
    unsigned short* __restrict__ C2,
    const float* __restrict__ w3, float* __restrict__ partials) {
    __shared__ unsigned short As0[128 * 40], As1[128 * 40], As2[128 * 40];
    __shared__ unsigned short Bs0[128 * 40], Bs1[128 * 40], Bs2[128 * 40];
    int t = threadIdx.x;
    int bid = blockIdx.x;
    // 8x8 supertile swizzle: 8 consecutive m-blocks share B in L2/L3
    int sm = bid >> 6, idx = bid & 63;
    int bm = ((sm << 3) + (idx & 7)) << 7;
    int bn = (idx >> 3) << 7;
    int lane = t & 63, wv = t >> 6;
    int wm = (wv >> 1) * 64, wn = (wv & 1) * 64;
    int lr = lane & 15, qq = lane >> 4;

    f32x4 acc[4][4] = {};

    for (int k0 = 0; k0 < Kp; k0 += 32) {
#pragma unroll
        for (int qi = 0; qi < 2; ++qi) {
            int u = qi * 256 + t;
            int m = u >> 2, blk = u & 3;
            size_t ga = (size_t)(bm + m) * Kp + k0 + blk * 8;
            size_t gb = (size_t)(bn + m) * Kp + k0 + blk * 8;
            uint4 va0 = *(const uint4*)(A0 + ga);
            uint4 va1 = *(const uint4*)(A1 + ga);
            uint4 va2 = *(const uint4*)(A2 + ga);
            uint4 vb0 = *(const uint4*)(B0 + gb);
            uint4 vb1 = *(const uint4*)(B1 + gb);
            uint4 vb2 = *(const uint4*)(B2 + gb);
            int la = m * 40 + blk * 8;
            *(uint4*)&As0[la] = va0;
            *(uint4*)&As1[la] = va1;
            *(uint4*)&As2[la] = va2;
            *(uint4*)&Bs0[la] = vb0;
            *(uint4*)&Bs1[la] = vb1;
            *(uint4*)&Bs2[la] = vb2;
        }
        __syncthreads();
        short8 a0[4], a1[4], a2[4];
#pragma unroll
        for (int i = 0; i < 4; ++i) {
            int ra = (wm + i * 16 + lr) * 40 + qq * 8;
            a0[i] = *(const short8*)&As0[ra];
            a1[i] = *(const short8*)&As1[ra];
            a2[i] = *(const short8*)&As2[ra];
        }
#pragma unroll
        for (int j = 0; j < 4; ++j) {
            int rb = (wn + j * 16 + lr) * 40 + qq * 8;
            short8 b0 = *(const short8*)&Bs0[rb];
            short8 b1 = *(const short8*)&Bs1[rb];
            short8 b2 = *(const short8*)&Bs2[rb];
#pragma unroll
            for (int i = 0; i < 4; ++i) {
                acc[i][j] = __builtin_amdgcn_mfma_f32_16x16x32_bf16(a2[i], b0, acc[i][j], 0, 0, 0);
                acc[i][j] = __builtin_amdgcn_mfma_f32_16x16x32_bf16(a0[i], b2, acc[i][j], 0, 0, 0);
                acc[i][j] = __builtin_amdgcn_mfma_f32_16x16x32_bf16(a1[i], b1, acc[i][j], 0, 0, 0);
                acc[i][j] = __builtin_amdgcn_mfma_f32_16x16x32_bf16(a1[i], b0, acc[i][j], 0, 0, 0);
                acc[i][j] = __builtin_amdgcn_mfma_f32_16x16x32_bf16(a0[i], b1, acc[i][j], 0, 0, 0);
                acc[i][j] = __builtin_amdgcn_mfma_f32_16x16x32_bf16(a0[i], b0, acc[i][j], 0, 0, 0);
            }
        }
        __syncthreads();
    }

    if (mode == 0) {
#pragma unroll
        for (int i = 0; i < 4; ++i)
#pragma unroll
            for (int j = 0; j < 4; ++j)
#pragma unroll
                for (int r = 0; r < 4; ++r) {
                    int m = bm + wm + i * 16 + qq * 4 + r;   // C/D: row = quad*4+reg
                    int n = bn + wn + j * 16 + lr;           //      col = lane&15
                    float v = acc[i][j][r] + (n < nreal ? bias[n] : 0.f);
                    v = fmaxf(v, 0.f);
                    store_split3(C0, C1, C2, (size_t)m * NP + n, v);
                }
    } else {
        int pid = ((bn >> 7) << 1) | (wn >> 6);  // 0..15
#pragma unroll
        for (int i = 0; i < 4; ++i)
#pragma unroll
            for (int r = 0; r < 4; ++r) {
                float p = 0.f;
#pragma unroll
                for (int j = 0; j < 4; ++j) {
                    int n = bn + wn + j * 16 + lr;
                    float v = acc[i][j][r] + (n < nreal ? bias[n] : 0.f);
                    v = fmaxf(v, 0.f);
                    p += v * (n < nreal ? w3[n] : 0.f);
                }
                p += __shfl_xor(p, 1);
                p += __shfl_xor(p, 2);
                p += __shfl_xor(p, 4);
                p += __shfl_xor(p, 8);
                if (lr == 0) {
                    int m = bm + wm + i * 16 + qq * 4 + r;
                    partials[(size_t)m * 16 + pid] = p;
                }
            }
    }
}

// ---------------- deterministic score finalize ----------------
__global__ void score_final(const float* __restrict__ partials, const float* __restrict__ b3,
                            const float* __restrict__ width_s, const int* __restrict__ starts,
                            const int* __restrict__ ends, float* __restrict__ out) {
    int c = blockIdx.x * 256 + threadIdx.x;
    if (c >= NUM_CAND) return;
    float s = b3[0] + width_s[ends[c] - starts[c]];
#pragma unroll
    for (int p = 0; p < 16; ++p) s += partials[(size_t)c * 16 + p];
    out[c] = s;
}

// ---------------- exact counting rank-sort: 256 blocks ----------------
__global__ __launch_bounds__(256) void rank_kernel(const float* __restrict__ scores,
                                                   const int* __restrict__ starts,
                                                   const int* __restrict__ ends,
                                                   unsigned short* __restrict__ ord_g,
                                                   unsigned int* __restrict__ se_g) {
    __shared__ unsigned long long kk[NUM_CAND];  // 64 KB
    int t = threadIdx.x;
    for (int i = t; i < NUM_CAND; i += 256) {
        unsigned int b = __float_as_uint(scores[i]);
        unsigned int u = b ^ ((b & 0x80000000u) ? 0xFFFFFFFFu : 0x80000000u);
        unsigned int hi = ~u;
        kk[i] = ((unsigned long long)hi << 32) | (unsigned int)i;
    }
    __syncthreads();
    int c = blockIdx.x * 32 + (t >> 3);      // candidate handled by this 8-lane group
    int seg = (t & 7) * 1024;
    unsigned long long mykey = kk[c];
    int cnt = 0;
    for (int i = seg; i < seg + 1024; ++i) cnt += (kk[i] < mykey) ? 1 : 0;
    cnt += __shfl_xor(cnt, 1);
    cnt += __shfl_xor(cnt, 2);
    cnt += __shfl_xor(cnt, 4);
    if ((t & 7) == 0) {
        int idx = (int)(mykey & 0xFFFFFFFFull);
        int rank = cnt;
        ord_g[rank] = (unsigned short)idx;
        se_g[rank] = ((unsigned int)starts[idx] << 16) | (unsigned int)ends[idx];
    }
}

// ---------------- speculative-chunked greedy crossing-NMS + final small sort ----------------
// r7 latency fixes: (1) state split into me32 (max_end+1, init 0) / ms32 (min_start, init 2048)
// so accept updates are fire-and-forget LDS atomicMax/atomicMin — no RMW round-trip on the
// accept critical path; (2) chunk-eval loads pinned as a batch via sched_barrier(0) so the
// scheduler cannot pair each ds_read with its consumer (which serialized 30x120-cyc in r6).
// NMS decision logic unchanged (verified r2/r4/r5/r6).
__global__ __launch_bounds__(1024) void select_kernel(const float* scores,
                                                      const int* __restrict__ starts,
                                                      const int* __restrict__ ends,
                                                      const unsigned short* __restrict__ ord_g,
                                                      const unsigned int* __restrict__ se_g,
                                                      float* out, int* top_idx_ws) {
    __shared__ unsigned short ord_arr[NUM_CAND];   // 16 KB
    __shared__ unsigned int se_arr[NUM_CAND];      // 32 KB
    __shared__ unsigned int me32[NUM_WORDS];       //  8 KB  (accepted max_end+1; 0 = none)
    __shared__ unsigned int ms32[NUM_WORDS];       //  8 KB  (accepted min_start; 2048 = none)
    __shared__ unsigned short sel[1024];           //  2 KB
    __shared__ unsigned long long fkeys[1024];     //  8 KB
    __shared__ int count_sh;
    int t = threadIdx.x;

    for (int i = t; i < NUM_CAND; i += 1024) {
        ord_arr[i] = ord_g[i];
        se_arr[i] = se_g[i];
    }
    for (int i = t; i < NUM_WORDS; i += 1024) {
        me32[i] = 0u;
        ms32[i] = (unsigned int)NUM_WORDS;
    }
    if (t == 0) count_sh = 0;
    __syncthreads();

    if (t < 64) {
        int count = 0;
        for (int i = 0; i < NUM_CAND && count < TOP_NUM; i += 64) {
            int c = i + t;  // NUM_CAND % 64 == 0, always valid
            unsigned int sev = se_arr[c];
            int s = (int)(sev >> 16), e = (int)(sev & 0xFFFFu);
            // batched state reads (indices clamped into [s,e], always in-bounds);
            // sched_barrier pins all 60 loads before any consumption.
            unsigned int mv[MSW], sv[MSW];
#pragma unroll
            for (int w = 0; w < MSW; ++w) {
                int j = s + w;
                mv[w] = me32[(j <= e) ? j : e];
            }
#pragma unroll
            for (int w = 0; w < MSW; ++w) {
                int j = s + w;
                sv[w] = ms32[(j <= e) ? j : e];
            }
            __builtin_amdgcn_sched_barrier(0);
            int me = (int)mv[0] - 1;
            bool crossed = (s < e) && ((int)sv[0] < s);
#pragma unroll
            for (int w = 1; w < MSW; ++w) {
                int j = s + w;
                bool in = (j <= e);
                int mej = (int)mv[w] - 1;
                int msj = (int)sv[w];
                crossed = crossed || (in && ((mej > e) || ((j < e) && (msj < s))));
            }
            bool spec = !crossed && (me != e);
            unsigned long long window = ~0ull;
            while (true) {
                unsigned long long b = __ballot(spec) & window;
                if (b == 0ull) break;
                int f = __ffsll((unsigned long long)b) - 1;
                unsigned int sef = __builtin_amdgcn_readlane(sev, (unsigned int)f);
                int sf = (int)(sef >> 16), ef = (int)(sef & 0xFFFFu);
                if (t == 0) {
                    sel[count] = ord_arr[i + f];
                    atomicMax(&me32[sf], (unsigned int)(ef + 1));  // fire-and-forget ds_max
                    atomicMin(&ms32[ef], (unsigned int)sf);        // fire-and-forget ds_min
                }
                count++;
                if (count >= TOP_NUM) break;
                window &= (f >= 63) ? 0ull : (~0ull << (f + 1));
                if (t > f) {
                    if (s == sf) me = max(me, ef);
                    crossed = crossed || ((s < sf) && (sf <= e) && (ef > e))
                                      || ((sf < s) && (s <= ef) && (ef < e));
                    spec = !crossed && (me != e);
                }
            }
        }
        if (t == 0) count_sh = count;
    }
    __syncthreads();
    int count = count_sh;

    // final sort of selected spans by (start*2048 + end), pad to 1024 with MAX keys
    {
        unsigned long long k;
        if (t < count) {
            int idx = (int)sel[t];
            unsigned int key32 = (unsigned int)(starts[idx] * NUM_WORDS + ends[idx]);
            k = ((unsigned long long)key32 << 32) | (unsigned int)idx;
        } else {
            k = 0xFFFFFFFFFFFFFFFFull;
        }
        fkeys[t] = k;
    }
    __syncthreads();
    for (int size = 2; size <= 1024; size <<= 1) {
        for (int stride = size >> 1; stride > 0; stride >>= 1) {
            int ixj = t ^ stride;
            if (ixj > t) {
                bool up = ((t & size) == 0);
                unsigned long long a = fkeys[t], b = fkeys[ixj];
                if ((a > b) == up) { fkeys[t] = b; fkeys[ixj] = a; }
            }
            __syncthreads();
        }
    }

    for (int i = t; i < TOP_NUM; i += 1024) {
        int fi = (i < count) ? (int)(fkeys[i] & 0xFFFFFFFFull)
                             : (int)(fkeys[0] & 0xFFFFFFFFull);
        out[OUT_TOPIDX + i] = (float)fi;
        out[OUT_TSTART + i] = (float)starts[fi];
        out[OUT_TEND + i] = (float)ends[fi];
        out[OUT_TSCORE + i] = scores[fi];
        top_idx_ws[i] = fi;
    }
}

// ---------------- gather top_span_emb rows (reconstruct fp32 = a0+a1+a2) ----------------
__global__ void gather_emb(const unsigned short* __restrict__ A0,
                           const unsigned short* __restrict__ A1,
                           const unsigned short* __restrict__ A2,
                           const int* __restrict__ top_idx_ws, float* __restrict__ out) {
    int r = blockIdx.x;
    int idx = top_idx_ws[r];
    const unsigned short* s0 = A0 + (size_t)idx * KP1;
    const unsigned short* s1 = A1 + (size_t)idx * KP1;
    const unsigned short* s2 = A2 + (size_t)idx * KP1;
    float* dst = out + OUT_TEMB + (size_t)r * SPAN_DIM;
    for (int h = threadIdx.x; h < SPAN_DIM; h += blockDim.x)
        dst[h] = bf16_to_f(s0[h]) + bf16_to_f(s1[h]) + bf16_to_f(s2[h]);
}

extern "C" void kernel_launch(void* const* d_in, const int* in_sizes, int n_in,
                              void* d_out, int out_size, void* d_ws, size_t ws_size,
                              hipStream_t stream) {
    const float* mention_doc = (const float*)d_in[0];
    const float* span_width_emb = (const float*)d_in[1];
    const float* head_w = (const float*)d_in[2];
    const float* head_b = (const float*)d_in[3];
    const float* m_w1 = (const float*)d_in[4];
    const float* m_b1 = (const float*)d_in[5];
    const float* m_w2 = (const float*)d_in[6];
    const float* m_b2 = (const float*)d_in[7];
    const float* m_w3 = (const float*)d_in[8];
    const float* m_b3 = (const float*)d_in[9];
    const float* width_prior_emb = (const float*)d_in[10];
    const float* w_w1 = (const float*)d_in[11];
    const float* w_b1 = (const float*)d_in[12];
    const float* w_w2 = (const float*)d_in[13];
    const float* w_b2 = (const float*)d_in[14];
    const float* w_w3 = (const float*)d_in[15];
    const float* w_b3 = (const float*)d_in[16];
    const int* cand_starts = (const int*)d_in[17];
    const int* cand_ends = (const int*)d_in[18];

    char* w = (char*)d_ws;
    const size_t szA = (size_t)NUM_CAND * KP1 * 2;   // 38.27 MB each
    const size_t szH = (size_t)NUM_CAND * NP * 2;    // 16.78 MB each
    const size_t szW1 = (size_t)NP * KP1 * 2;        // 4.78 MB each
    const size_t szW2 = (size_t)NP * KP2 * 2;        // 2.10 MB each
    unsigned short* A0 = (unsigned short*)w;
    unsigned short* A1 = (unsigned short*)(w + szA);
    unsigned short* A2 = (unsigned short*)(w + 2 * szA);
    char* p = w + 3 * szA;
    unsigned short* h0 = (unsigned short*)p;
    unsigned short* h1 = (unsigned short*)(p + szH);
    unsigned short* h2 = (unsigned short*)(p + 2 * szH);
    p += 3 * szH;
    unsigned short* w1t0 = (unsigned short*)p;
    unsigned short* w1t1 = (unsigned short*)(p + szW1);
    unsigned short* w1t2 = (unsigned short*)(p + 2 * szW1);
    p += 3 * szW1;
    unsigned short* w2t0 = (unsigned short*)p;
    unsigned short* w2t1 = (unsigned short*)(p + szW2);
    unsigned short* w2t2 = (unsigned short*)(p + 2 * szW2);
    p += 3 * szW2;
    float* partials = (float*)p;                    // 8192*16 floats
    p += (size_t)NUM_CAND * 16 * 4;
    unsigned short* ord_g = (unsigned short*)p;     // 8192 u16
    p += (size_t)NUM_CAND * 2;
    unsigned int* se_g = (unsigned int*)p;          // 8192 u32
    p += (size_t)NUM_CAND * 4;
    float* head_s = (float*)p;                      // 2048 floats
    float* width_s = (float*)(p + 8192);            // 32 floats
    int* top_idx_ws = (int*)(p + 8192 + 128);       // 1024 ints

    size_t need = (size_t)(p - w) + 8192 + 128 + 4096;
    if (ws_size < need) {
        fprintf(stderr, "kernel_launch: ws too small (%zu < %zu)\n", ws_size, need);
    }

    float* out = (float*)d_out;

    head_kernel<<<NUM_WORDS / 4, 256, 0, stream>>>(mention_doc, head_w, head_b, head_s);
    width_kernel<<<MSW, 256, 0, stream>>>(width_prior_emb, w_w1, w_b1, w_w2, w_b2, w_w3, w_b3,
                                          width_s);
    convert_wt<<<dim3((KP1 + 255) / 256, NP), 256, 0, stream>>>(m_w1, SPAN_DIM, FFNN_DIM, KP1,
                                                                w1t0, w1t1, w1t2);
    convert_wt<<<dim3((KP2 + 255) / 256, NP), 256, 0, stream>>>(m_w2, FFNN_DIM, FFNN_DIM, KP2,
                                                                w2t0, w2t1, w2t2);
    span_emb_kernel<<<NUM_CAND, 256, 0, stream>>>(mention_doc, span_width_emb, head_s,
                                                  cand_starts, cand_ends, A0, A1, A2);
    gemm6<<<512, 256, 0, stream>>>(A0, A1, A2, w1t0, w1t1, w1t2, m_b1, FFNN_DIM, KP1, 0,
                                   h0, h1, h2, nullptr, nullptr);
    gemm6<<<512, 256, 0, stream>>>(h0, h1, h2, w2t0, w2t1, w2t2, m_b2, FFNN_DIM, KP2, 1,
                                   nullptr, nullptr, nullptr, m_w3, partials);
    score_final<<<NUM_CAND / 256, 256, 0, stream>>>(partials, m_b3, width_s, cand_starts,
                                                    cand_ends, out);
    rank_kernel<<<NUM_CAND / 32, 256, 0, stream>>>(out, cand_starts, cand_ends, ord_g, se_g);
    select_kernel<<<1, 1024, 0, stream>>>(out, cand_starts, cand_ends, ord_g, se_g, out,
                                          top_idx_ws);
    gather_emb<<<TOP_NUM, 256, 0, stream>>>(A0, A1, A2, top_idx_ws, out);
}